// Round 3
// baseline (3489.860 us; speedup 1.0000x reference)
//
#include <hip/hip_runtime.h>
#include <cstdint>
#include <cstddef>

#define BN_EPS 1e-5f
#define SCAN_T 256
#define SCAN_CHUNK 1024

// ---------------- BN stats: per-block partial sums (no atomics) ----------------
__global__ void k_stats(const float* __restrict__ X, const float* __restrict__ imp,
                        float* __restrict__ ps, float* __restrict__ pq, int n) {
    const int c = threadIdx.x;           // 0..127 = channel
    float s = 0.f, q = 0.f;
    for (int r = blockIdx.x; r < n; r += gridDim.x) {
        float v = X[(size_t)r * 128 + c] * imp[r];
        s += v; q += v * v;
    }
    ps[blockIdx.x * 128 + c] = s;
    pq[blockIdx.x * 128 + c] = q;
}

__global__ void k_finalize(const float* __restrict__ ps, const float* __restrict__ pq,
                           const float* __restrict__ gamma, const float* __restrict__ beta,
                           float* __restrict__ scale, float* __restrict__ shift,
                           int nblocks, float inv_n) {
    const int c = threadIdx.x;           // 128 threads
    float s = 0.f, q = 0.f;
    for (int b = 0; b < nblocks; ++b) { s += ps[b * 128 + c]; q += pq[b * 128 + c]; }
    float mu  = s * inv_n;
    float var = fmaf(-mu, mu, q * inv_n);   // biased variance
    float rs  = rsqrtf(var + BN_EPS);
    float sc  = gamma[c] * rs;
    scale[c] = sc;
    shift[c] = fmaf(-mu, sc, beta[c]);
}

// ---------------- CSR-by-destination build ----------------
__global__ void k_hist(const int* __restrict__ dst, int* __restrict__ deg, int e) {
    int i = blockIdx.x * blockDim.x + threadIdx.x;
    const int stride = gridDim.x * blockDim.x;
    for (; i < e; i += stride) atomicAdd(&deg[dst[i]], 1);
}

__global__ void k_chunk_sum(const int* __restrict__ deg, int* __restrict__ part, int n) {
    __shared__ int sm[SCAN_T];
    const int t = threadIdx.x;
    const int base = blockIdx.x * SCAN_CHUNK + t * 4;
    int s = 0;
#pragma unroll
    for (int j = 0; j < 4; ++j) { int idx = base + j; if (idx < n) s += deg[idx]; }
    sm[t] = s;
    __syncthreads();
    for (int off = SCAN_T / 2; off > 0; off >>= 1) {
        if (t < off) sm[t] += sm[t + off];
        __syncthreads();
    }
    if (t == 0) part[blockIdx.x] = sm[0];
}

__global__ void k_scan_part(int* __restrict__ part, int nparts, int* __restrict__ total_out) {
    __shared__ int sm[128];
    const int t = threadIdx.x;          // 128 threads
    int v = (t < nparts) ? part[t] : 0;
    const int mys = v;
    sm[t] = v;
    __syncthreads();
    for (int off = 1; off < 128; off <<= 1) {
        int u = (t >= off) ? sm[t - off] : 0;
        __syncthreads();
        sm[t] += u;
        __syncthreads();
    }
    if (t < nparts) part[t] = sm[t] - mys;
    if (t == 127) *total_out = sm[127];
}

__global__ void k_chunk_scan(const int* __restrict__ deg, const int* __restrict__ part,
                             int* __restrict__ rowptr, int* __restrict__ cursor, int n) {
    __shared__ int sm[SCAN_T];
    const int t = threadIdx.x;
    const int base = blockIdx.x * SCAN_CHUNK + t * 4;
    int l[4];
    int s = 0;
#pragma unroll
    for (int j = 0; j < 4; ++j) { int idx = base + j; l[j] = (idx < n) ? deg[idx] : 0; s += l[j]; }
    const int mys = s;
    sm[t] = s;
    __syncthreads();
    for (int off = 1; off < SCAN_T; off <<= 1) {
        int u = (t >= off) ? sm[t - off] : 0;
        __syncthreads();
        sm[t] += u;
        __syncthreads();
    }
    int excl = sm[t] - mys + part[blockIdx.x];
#pragma unroll
    for (int j = 0; j < 4; ++j) {
        int idx = base + j;
        if (idx < n) { rowptr[idx] = excl; cursor[idx] = excl; excl += l[j]; }
    }
}

__global__ void k_scatter(const int* __restrict__ src, const int* __restrict__ dst,
                          int* __restrict__ cursor, int2* __restrict__ ed2, int e) {
    int i = blockIdx.x * blockDim.x + threadIdx.x;
    const int stride = gridDim.x * blockDim.x;
    for (; i < e; i += stride) {
        const int d = dst[i];
        const int p = atomicAdd(&cursor[d], 1);
        ed2[p] = make_int2(src[i], d);
    }
}

// ---------------- V1 = BN(X*imp) @ W1  (BN-apply fused, 128->64) ----------------
__global__ __launch_bounds__(256) void k_pregemm(
        const float* __restrict__ X, const float* __restrict__ imp,
        const float* __restrict__ scale, const float* __restrict__ shift,
        const float* __restrict__ W1, float* __restrict__ V1, int n) {
    __shared__ float tile[64 * 129];
    __shared__ float Wl[128 * 64];
    const int t = threadIdx.x;
    for (int i = t; i < 128 * 64 / 4; i += 256)
        reinterpret_cast<float4*>(Wl)[i] = reinterpret_cast<const float4*>(W1)[i];

    const int nodeL = t >> 2, q = t & 3;
    const int node = blockIdx.x * 64 + nodeL;
    // stage BN-normalized row; channels q*4+16j .. +3 (interleaved for bank spread)
    if (node < n) {
        const float im = imp[node];
#pragma unroll
        for (int j = 0; j < 8; ++j) {
            const int c = q * 4 + j * 16;
            const float4 x  = *reinterpret_cast<const float4*>(X + (size_t)node * 128 + c);
            const float4 sc = *reinterpret_cast<const float4*>(scale + c);
            const float4 sh = *reinterpret_cast<const float4*>(shift + c);
            float* tr = tile + nodeL * 129 + c;
            tr[0] = fmaf(x.x * im, sc.x, sh.x);
            tr[1] = fmaf(x.y * im, sc.y, sh.y);
            tr[2] = fmaf(x.z * im, sc.z, sh.z);
            tr[3] = fmaf(x.w * im, sc.w, sh.w);
        }
    } else {
#pragma unroll
        for (int j = 0; j < 8; ++j) {
            const int c = q * 4 + j * 16;
            float* tr = tile + nodeL * 129 + c;
            tr[0] = 0.f; tr[1] = 0.f; tr[2] = 0.f; tr[3] = 0.f;
        }
    }
    __syncthreads();

    const int j0 = q * 16;
    float acc[16];
#pragma unroll
    for (int i = 0; i < 16; ++i) acc[i] = 0.f;
#pragma unroll 4
    for (int k = 0; k < 128; ++k) {
        const float ak = tile[nodeL * 129 + k];
        const float4* w = reinterpret_cast<const float4*>(Wl + k * 64 + j0);
#pragma unroll
        for (int i = 0; i < 4; ++i) {
            const float4 wv = w[i];
            acc[4 * i + 0] = fmaf(ak, wv.x, acc[4 * i + 0]);
            acc[4 * i + 1] = fmaf(ak, wv.y, acc[4 * i + 1]);
            acc[4 * i + 2] = fmaf(ak, wv.z, acc[4 * i + 2]);
            acc[4 * i + 3] = fmaf(ak, wv.w, acc[4 * i + 3]);
        }
    }
    if (node < n) {
        float* o = V1 + (size_t)node * 64 + j0;
#pragma unroll
        for (int i = 0; i < 4; ++i)
            *reinterpret_cast<float4*>(o + 4 * i) =
                make_float4(acc[4 * i], acc[4 * i + 1], acc[4 * i + 2], acc[4 * i + 3]);
    }
}

// ---------------- GIN layer: agg(V) + b -> tanh -> h ; V_next = h @ Wn ----------------
// Block = 64-node tile. Phase A: stage V_self + edge-parallel LDS-atomic gather.
// Phase B: h = tanh(agg + b), write out-slice, write h back into tile.
// Phase C: dense 64x64 GEMM from LDS (lane=node broadcast reads, no shuffles).
template <bool FUSE_FC>
__global__ __launch_bounds__(256) void k_layer(
        const float* __restrict__ Vin, const float* __restrict__ bias,
        const float* __restrict__ Wn,
        float* __restrict__ outh,                 // out + colOff, stride 384
        float* __restrict__ nextp, int next_stride,  // compact V_next (64) or fc out slice (384)
        const int* __restrict__ rowptr, const int2* __restrict__ ed2, int n) {
    __shared__ float tile[64 * 65];
    __shared__ float Wl[64 * 64];
    const int t = threadIdx.x;
    for (int i = t; i < 64 * 64 / 4; i += 256)
        reinterpret_cast<float4*>(Wl)[i] = reinterpret_cast<const float4*>(Wn)[i];

    const int base = blockIdx.x * 64;
    const int nodeL = t >> 2, q = t & 3;
    const int node = base + nodeL;
    const int c0 = q * 16;

    // ---- phase A0: self term
    if (node < n) {
#pragma unroll
        for (int i = 0; i < 4; ++i) {
            const float4 v = *reinterpret_cast<const float4*>(Vin + (size_t)node * 64 + c0 + 4 * i);
            float* tr = tile + nodeL * 65 + c0 + 4 * i;
            tr[0] = v.x; tr[1] = v.y; tr[2] = v.z; tr[3] = v.w;
        }
    } else {
#pragma unroll
        for (int i = 0; i < 16; ++i) tile[nodeL * 65 + c0 + i] = 0.f;
    }
    __syncthreads();

    // ---- phase A1: edge-parallel gather-accumulate (16 groups x 16 lanes)
    {
        const int e0 = rowptr[base];
        const int e1 = rowptr[(base + 64 < n) ? base + 64 : n];
        const int g   = t >> 4;       // 0..15
        const int gl4 = (t & 15) * 4; // channel offset
        int p = e0 + g;
        for (; p + 48 < e1; p += 64) {
            const int2 sd0 = ed2[p];
            const int2 sd1 = ed2[p + 16];
            const int2 sd2 = ed2[p + 32];
            const int2 sd3 = ed2[p + 48];
            const float4 v0 = *reinterpret_cast<const float4*>(Vin + (size_t)sd0.x * 64 + gl4);
            const float4 v1 = *reinterpret_cast<const float4*>(Vin + (size_t)sd1.x * 64 + gl4);
            const float4 v2 = *reinterpret_cast<const float4*>(Vin + (size_t)sd2.x * 64 + gl4);
            const float4 v3 = *reinterpret_cast<const float4*>(Vin + (size_t)sd3.x * 64 + gl4);
            float* t0 = tile + (sd0.y - base) * 65 + gl4;
            float* t1 = tile + (sd1.y - base) * 65 + gl4;
            float* t2 = tile + (sd2.y - base) * 65 + gl4;
            float* t3 = tile + (sd3.y - base) * 65 + gl4;
            atomicAdd(t0 + 0, v0.x); atomicAdd(t0 + 1, v0.y); atomicAdd(t0 + 2, v0.z); atomicAdd(t0 + 3, v0.w);
            atomicAdd(t1 + 0, v1.x); atomicAdd(t1 + 1, v1.y); atomicAdd(t1 + 2, v1.z); atomicAdd(t1 + 3, v1.w);
            atomicAdd(t2 + 0, v2.x); atomicAdd(t2 + 1, v2.y); atomicAdd(t2 + 2, v2.z); atomicAdd(t2 + 3, v2.w);
            atomicAdd(t3 + 0, v3.x); atomicAdd(t3 + 1, v3.y); atomicAdd(t3 + 2, v3.z); atomicAdd(t3 + 3, v3.w);
        }
        for (; p < e1; p += 16) {
            const int2 sd = ed2[p];
            const float4 v = *reinterpret_cast<const float4*>(Vin + (size_t)sd.x * 64 + gl4);
            float* tr = tile + (sd.y - base) * 65 + gl4;
            atomicAdd(tr + 0, v.x); atomicAdd(tr + 1, v.y); atomicAdd(tr + 2, v.z); atomicAdd(tr + 3, v.w);
        }
    }
    __syncthreads();

    // ---- phase B: h = tanh(agg + bias); write out slice; write back to tile
    {
        float h[16];
#pragma unroll
        for (int i = 0; i < 4; ++i) {
            const float4 bb = *reinterpret_cast<const float4*>(bias + c0 + 4 * i);
            const float* tr = tile + nodeL * 65 + c0 + 4 * i;
            h[4 * i + 0] = tanhf(tr[0] + bb.x);
            h[4 * i + 1] = tanhf(tr[1] + bb.y);
            h[4 * i + 2] = tanhf(tr[2] + bb.z);
            h[4 * i + 3] = tanhf(tr[3] + bb.w);
        }
#pragma unroll
        for (int i = 0; i < 16; ++i) tile[nodeL * 65 + c0 + i] = h[i];
        if (node < n) {
            float* o = outh + (size_t)node * 384 + c0;
#pragma unroll
            for (int i = 0; i < 4; ++i)
                *reinterpret_cast<float4*>(o + 4 * i) =
                    make_float4(h[4 * i], h[4 * i + 1], h[4 * i + 2], h[4 * i + 3]);
        }
    }
    __syncthreads();

    // ---- phase C: V_next = h @ Wn (or fc: tanh(h @ Wf))
    {
        const int j0 = q * 16;
        float acc[16];
#pragma unroll
        for (int i = 0; i < 16; ++i) acc[i] = 0.f;
#pragma unroll 4
        for (int k = 0; k < 64; ++k) {
            const float ak = tile[nodeL * 65 + k];
            const float4* w = reinterpret_cast<const float4*>(Wl + k * 64 + j0);
#pragma unroll
            for (int i = 0; i < 4; ++i) {
                const float4 wv = w[i];
                acc[4 * i + 0] = fmaf(ak, wv.x, acc[4 * i + 0]);
                acc[4 * i + 1] = fmaf(ak, wv.y, acc[4 * i + 1]);
                acc[4 * i + 2] = fmaf(ak, wv.z, acc[4 * i + 2]);
                acc[4 * i + 3] = fmaf(ak, wv.w, acc[4 * i + 3]);
            }
        }
        if (node < n) {
            float* o = nextp + (size_t)node * next_stride + j0;
#pragma unroll
            for (int i = 0; i < 4; ++i) {
                float4 r;
                if (FUSE_FC) {
                    r = make_float4(tanhf(acc[4 * i]), tanhf(acc[4 * i + 1]),
                                    tanhf(acc[4 * i + 2]), tanhf(acc[4 * i + 3]));
                } else {
                    r = make_float4(acc[4 * i], acc[4 * i + 1], acc[4 * i + 2], acc[4 * i + 3]);
                }
                *reinterpret_cast<float4*>(o + 4 * i) = r;
            }
        }
    }
}

// ---------------- launch ----------------
extern "C" void kernel_launch(void* const* d_in, const int* in_sizes, int n_in,
                              void* d_out, int out_size, void* d_ws, size_t ws_size,
                              hipStream_t stream) {
    const float* X     = (const float*)d_in[0];
    const float* imp   = (const float*)d_in[1];
    const int*   ei    = (const int*)d_in[2];
    const float* gamma = (const float*)d_in[3];
    const float* beta  = (const float*)d_in[4];
    const float* W1 = (const float*)d_in[5];
    const float* b1 = (const float*)d_in[6];
    const float* W2 = (const float*)d_in[7];
    const float* b2 = (const float*)d_in[8];
    const float* W3 = (const float*)d_in[9];
    const float* b3 = (const float*)d_in[10];
    const float* W4 = (const float*)d_in[11];
    const float* b4 = (const float*)d_in[12];
    const float* W5 = (const float*)d_in[13];
    const float* b5 = (const float*)d_in[14];
    const float* Wf = (const float*)d_in[15];
    float* out = (float*)d_out;

    const int n = in_sizes[1];        // N
    const int e = in_sizes[2] / 2;    // E
    const int* src = ei;
    const int* dst = ei + e;

    // workspace carve (256B aligned)
    char* p = (char*)d_ws;
    auto carve = [&](size_t bytes) { char* r = p; p += (bytes + 255) & ~(size_t)255; return r; };
    int*   deg    = (int*)carve((size_t)n * sizeof(int));
    int*   rowptr = (int*)carve((size_t)(n + 1) * sizeof(int));
    int*   cursor = (int*)carve((size_t)n * sizeof(int));
    int2*  ed2    = (int2*)carve((size_t)e * sizeof(int2));
    const int nchunks = (n + SCAN_CHUNK - 1) / SCAN_CHUNK;
    int*   part   = (int*)carve((size_t)nchunks * sizeof(int));
    const int STATS_B = 256;
    float* ps    = (float*)carve((size_t)STATS_B * 128 * sizeof(float));
    float* pq    = (float*)carve((size_t)STATS_B * 128 * sizeof(float));
    float* scale = (float*)carve(128 * sizeof(float));
    float* shift = (float*)carve(128 * sizeof(float));
    float* VA    = (float*)carve((size_t)n * 64 * sizeof(float));
    float* VB    = (float*)carve((size_t)n * 64 * sizeof(float));

    const int ntiles = (n + 63) / 64;

    // BN stats
    k_stats<<<STATS_B, 128, 0, stream>>>(X, imp, ps, pq, n);
    k_finalize<<<1, 128, 0, stream>>>(ps, pq, gamma, beta, scale, shift, STATS_B, 1.0f / (float)n);

    // CSR build (by destination) with int2{src,dst} payload
    hipMemsetAsync(deg, 0, (size_t)n * sizeof(int), stream);
    k_hist<<<1024, 256, 0, stream>>>(dst, deg, e);
    k_chunk_sum<<<nchunks, SCAN_T, 0, stream>>>(deg, part, n);
    k_scan_part<<<1, 128, 0, stream>>>(part, nchunks, rowptr + n);
    k_chunk_scan<<<nchunks, SCAN_T, 0, stream>>>(deg, part, rowptr, cursor, n);
    k_scatter<<<1024, 256, 0, stream>>>(src, dst, cursor, ed2, e);

    // V1 = BN(X*imp) @ W1
    k_pregemm<<<ntiles, 256, 0, stream>>>(X, imp, scale, shift, W1, VA, n);

    // layers: h_l = tanh(agg(V_l)+b_l); V_{l+1} = h_l @ W_{l+1}; last fuses fc
    k_layer<false><<<ntiles, 256, 0, stream>>>(VA, b1, W2, out + 0,   VB, 64,  rowptr, ed2, n);
    k_layer<false><<<ntiles, 256, 0, stream>>>(VB, b2, W3, out + 64,  VA, 64,  rowptr, ed2, n);
    k_layer<false><<<ntiles, 256, 0, stream>>>(VA, b3, W4, out + 128, VB, 64,  rowptr, ed2, n);
    k_layer<false><<<ntiles, 256, 0, stream>>>(VB, b4, W5, out + 192, VA, 64,  rowptr, ed2, n);
    k_layer<true ><<<ntiles, 256, 0, stream>>>(VA, b5, Wf, out + 256, out + 320, 384, rowptr, ed2, n);
}

// Round 4
// 865.024 us; speedup vs baseline: 4.0344x; 4.0344x over previous
//
#include <hip/hip_runtime.h>
#include <cstdint>
#include <cstddef>

#define BN_EPS 1e-5f
#define SCAN_T 256
#define SCAN_CHUNK 1024

__device__ __forceinline__ float tanh_fast(float x) {
    // tanh(x) = 1 - 2/(e^{2x}+1); exp overflow/underflow saturate correctly
    const float e = __expf(2.f * x);
    return 1.f - 2.f / (e + 1.f);
}

// ---------------- BN stats: per-block partial sums (no atomics) ----------------
__global__ void k_stats(const float* __restrict__ X, const float* __restrict__ imp,
                        float* __restrict__ ps, float* __restrict__ pq, int n) {
    const int c = threadIdx.x;           // 0..127 = channel
    float s = 0.f, q = 0.f;
    for (int r = blockIdx.x; r < n; r += gridDim.x) {
        float v = X[(size_t)r * 128 + c] * imp[r];
        s += v; q += v * v;
    }
    ps[blockIdx.x * 128 + c] = s;
    pq[blockIdx.x * 128 + c] = q;
}

__global__ void k_finalize(const float* __restrict__ ps, const float* __restrict__ pq,
                           const float* __restrict__ gamma, const float* __restrict__ beta,
                           float* __restrict__ scale, float* __restrict__ shift,
                           int nblocks, float inv_n) {
    const int c = threadIdx.x;           // 128 threads
    float s = 0.f, q = 0.f;
    for (int b = 0; b < nblocks; ++b) { s += ps[b * 128 + c]; q += pq[b * 128 + c]; }
    float mu  = s * inv_n;
    float var = fmaf(-mu, mu, q * inv_n);   // biased variance
    float rs  = rsqrtf(var + BN_EPS);
    float sc  = gamma[c] * rs;
    scale[c] = sc;
    shift[c] = fmaf(-mu, sc, beta[c]);
}

// ---------------- CSR-by-destination build ----------------
__global__ void k_hist(const int* __restrict__ dst, int* __restrict__ deg, int e) {
    int i = blockIdx.x * blockDim.x + threadIdx.x;
    const int stride = gridDim.x * blockDim.x;
    for (; i < e; i += stride) atomicAdd(&deg[dst[i]], 1);
}

__global__ void k_chunk_sum(const int* __restrict__ deg, int* __restrict__ part, int n) {
    __shared__ int sm[SCAN_T];
    const int t = threadIdx.x;
    const int base = blockIdx.x * SCAN_CHUNK + t * 4;
    int s = 0;
#pragma unroll
    for (int j = 0; j < 4; ++j) { int idx = base + j; if (idx < n) s += deg[idx]; }
    sm[t] = s;
    __syncthreads();
    for (int off = SCAN_T / 2; off > 0; off >>= 1) {
        if (t < off) sm[t] += sm[t + off];
        __syncthreads();
    }
    if (t == 0) part[blockIdx.x] = sm[0];
}

__global__ void k_scan_part(int* __restrict__ part, int nparts, int* __restrict__ total_out) {
    __shared__ int sm[128];
    const int t = threadIdx.x;          // 128 threads
    int v = (t < nparts) ? part[t] : 0;
    const int mys = v;
    sm[t] = v;
    __syncthreads();
    for (int off = 1; off < 128; off <<= 1) {
        int u = (t >= off) ? sm[t - off] : 0;
        __syncthreads();
        sm[t] += u;
        __syncthreads();
    }
    if (t < nparts) part[t] = sm[t] - mys;
    if (t == 127) *total_out = sm[127];
}

__global__ void k_chunk_scan(const int* __restrict__ deg, const int* __restrict__ part,
                             int* __restrict__ rowptr, int* __restrict__ cursor, int n) {
    __shared__ int sm[SCAN_T];
    const int t = threadIdx.x;
    const int base = blockIdx.x * SCAN_CHUNK + t * 4;
    int l[4];
    int s = 0;
#pragma unroll
    for (int j = 0; j < 4; ++j) { int idx = base + j; l[j] = (idx < n) ? deg[idx] : 0; s += l[j]; }
    const int mys = s;
    sm[t] = s;
    __syncthreads();
    for (int off = 1; off < SCAN_T; off <<= 1) {
        int u = (t >= off) ? sm[t - off] : 0;
        __syncthreads();
        sm[t] += u;
        __syncthreads();
    }
    int excl = sm[t] - mys + part[blockIdx.x];
#pragma unroll
    for (int j = 0; j < 4; ++j) {
        int idx = base + j;
        if (idx < n) { rowptr[idx] = excl; cursor[idx] = excl; excl += l[j]; }
    }
}

__global__ void k_scatter(const int* __restrict__ src, const int* __restrict__ dst,
                          int* __restrict__ cursor, int* __restrict__ csr, int e) {
    int i = blockIdx.x * blockDim.x + threadIdx.x;
    const int stride = gridDim.x * blockDim.x;
    for (; i < e; i += stride) {
        const int p = atomicAdd(&cursor[dst[i]], 1);
        csr[p] = src[i];
    }
}

// ---------------- V1 = BN(X*imp) @ W1  (BN-apply fused, 128->64) ----------------
__global__ __launch_bounds__(256) void k_pregemm(
        const float* __restrict__ X, const float* __restrict__ imp,
        const float* __restrict__ scale, const float* __restrict__ shift,
        const float* __restrict__ W1, float* __restrict__ V1, int n) {
    __shared__ float tile[64 * 129];
    __shared__ float Wl[128 * 64];
    const int t = threadIdx.x;
    for (int i = t; i < 128 * 64 / 4; i += 256)
        reinterpret_cast<float4*>(Wl)[i] = reinterpret_cast<const float4*>(W1)[i];

    const int nodeL = t >> 2, q = t & 3;
    const int node = blockIdx.x * 64 + nodeL;
    if (node < n) {
        const float im = imp[node];
#pragma unroll
        for (int j = 0; j < 8; ++j) {
            const int c = q * 4 + j * 16;
            const float4 x  = *reinterpret_cast<const float4*>(X + (size_t)node * 128 + c);
            const float4 sc = *reinterpret_cast<const float4*>(scale + c);
            const float4 sh = *reinterpret_cast<const float4*>(shift + c);
            float* tr = tile + nodeL * 129 + c;
            tr[0] = fmaf(x.x * im, sc.x, sh.x);
            tr[1] = fmaf(x.y * im, sc.y, sh.y);
            tr[2] = fmaf(x.z * im, sc.z, sh.z);
            tr[3] = fmaf(x.w * im, sc.w, sh.w);
        }
    } else {
#pragma unroll
        for (int j = 0; j < 8; ++j) {
            const int c = q * 4 + j * 16;
            float* tr = tile + nodeL * 129 + c;
            tr[0] = 0.f; tr[1] = 0.f; tr[2] = 0.f; tr[3] = 0.f;
        }
    }
    __syncthreads();

    const int j0 = q * 16;
    float acc[16];
#pragma unroll
    for (int i = 0; i < 16; ++i) acc[i] = 0.f;
#pragma unroll 4
    for (int k = 0; k < 128; ++k) {
        const float ak = tile[nodeL * 129 + k];
        const float4* w = reinterpret_cast<const float4*>(Wl + k * 64 + j0);
#pragma unroll
        for (int i = 0; i < 4; ++i) {
            const float4 wv = w[i];
            acc[4 * i + 0] = fmaf(ak, wv.x, acc[4 * i + 0]);
            acc[4 * i + 1] = fmaf(ak, wv.y, acc[4 * i + 1]);
            acc[4 * i + 2] = fmaf(ak, wv.z, acc[4 * i + 2]);
            acc[4 * i + 3] = fmaf(ak, wv.w, acc[4 * i + 3]);
        }
    }
    if (node < n) {
        float* o = V1 + (size_t)node * 64 + j0;
#pragma unroll
        for (int i = 0; i < 4; ++i)
            *reinterpret_cast<float4*>(o + 4 * i) =
                make_float4(acc[4 * i], acc[4 * i + 1], acc[4 * i + 2], acc[4 * i + 3]);
    }
}

// ---------------- gather: h = tanh(V_self + sum_j V_j + b), register-only ----------------
// One wave per dst node. 4 groups x 16 lanes; group g takes edges beg+g, beg+g+4, ...
// Each lane holds channels gl4..gl4+3 in registers. Batches of 4 edges -> 4 independent
// index loads + 4 independent float4 gathers in flight. No LDS, no atomics.
__global__ __launch_bounds__(256, 8) void k_gather(
        const float* __restrict__ Vin, const float* __restrict__ bias,
        float* __restrict__ outh,    // d_out + col, row stride 384
        const int* __restrict__ rowptr, const int* __restrict__ csr, int n) {
    const int lane = threadIdx.x & 63;
    const int grp  = lane >> 4;
    const int gl4  = (lane & 15) << 2;
    const int w = blockIdx.x * 4 + (threadIdx.x >> 6);
    if (w >= n) return;

    float4 acc = make_float4(0.f, 0.f, 0.f, 0.f);
    if (grp == 0)
        acc = *reinterpret_cast<const float4*>(Vin + (size_t)w * 64 + gl4);

    const int beg = rowptr[w], end = rowptr[w + 1];
    int p = beg + grp;
    for (; p + 12 < end; p += 16) {          // 4 edges for this group (stride 4)
        const int s0 = csr[p];
        const int s1 = csr[p + 4];
        const int s2 = csr[p + 8];
        const int s3 = csr[p + 12];
        const float4 v0 = *reinterpret_cast<const float4*>(Vin + (size_t)s0 * 64 + gl4);
        const float4 v1 = *reinterpret_cast<const float4*>(Vin + (size_t)s1 * 64 + gl4);
        const float4 v2 = *reinterpret_cast<const float4*>(Vin + (size_t)s2 * 64 + gl4);
        const float4 v3 = *reinterpret_cast<const float4*>(Vin + (size_t)s3 * 64 + gl4);
        acc.x += v0.x + v1.x + v2.x + v3.x;
        acc.y += v0.y + v1.y + v2.y + v3.y;
        acc.z += v0.z + v1.z + v2.z + v3.z;
        acc.w += v0.w + v1.w + v2.w + v3.w;
    }
    for (; p < end; p += 4) {
        const int s = csr[p];
        const float4 v = *reinterpret_cast<const float4*>(Vin + (size_t)s * 64 + gl4);
        acc.x += v.x; acc.y += v.y; acc.z += v.z; acc.w += v.w;
    }

    // combine the 4 group partials
    acc.x += __shfl_xor(acc.x, 16); acc.y += __shfl_xor(acc.y, 16);
    acc.z += __shfl_xor(acc.z, 16); acc.w += __shfl_xor(acc.w, 16);
    acc.x += __shfl_xor(acc.x, 32); acc.y += __shfl_xor(acc.y, 32);
    acc.z += __shfl_xor(acc.z, 32); acc.w += __shfl_xor(acc.w, 32);

    if (grp == 0) {
        const float4 bb = *reinterpret_cast<const float4*>(bias + gl4);
        float4 r;
        r.x = tanh_fast(acc.x + bb.x);
        r.y = tanh_fast(acc.y + bb.y);
        r.z = tanh_fast(acc.z + bb.z);
        r.w = tanh_fast(acc.w + bb.w);
        *reinterpret_cast<float4*>(outh + (size_t)w * 384 + gl4) = r;
    }
}

// ---------------- dense: out = hin @ W  (optionally tanh) ----------------
template <bool TANH>
__global__ __launch_bounds__(256) void k_dense(
        const float* __restrict__ hin, int in_stride,
        const float* __restrict__ W,
        float* __restrict__ outp, int out_stride, int n) {
    __shared__ float tile[64 * 65];
    __shared__ float Wl[64 * 64];
    const int t = threadIdx.x;
    for (int i = t; i < 64 * 64 / 4; i += 256)
        reinterpret_cast<float4*>(Wl)[i] = reinterpret_cast<const float4*>(W)[i];

    const int nodeL = t >> 2, q = t & 3;
    const int node = blockIdx.x * 64 + nodeL;
    if (node < n) {
#pragma unroll
        for (int i = 0; i < 4; ++i) {
            const float4 v = *reinterpret_cast<const float4*>(hin + (size_t)node * in_stride + q * 16 + 4 * i);
            float* tr = tile + nodeL * 65 + q * 16 + 4 * i;
            tr[0] = v.x; tr[1] = v.y; tr[2] = v.z; tr[3] = v.w;
        }
    } else {
#pragma unroll
        for (int i = 0; i < 16; ++i) tile[nodeL * 65 + q * 16 + i] = 0.f;
    }
    __syncthreads();

    const int j0 = q * 16;
    float acc[16];
#pragma unroll
    for (int i = 0; i < 16; ++i) acc[i] = 0.f;
#pragma unroll 4
    for (int k = 0; k < 64; ++k) {
        const float ak = tile[nodeL * 65 + k];
        const float4* w = reinterpret_cast<const float4*>(Wl + k * 64 + j0);
#pragma unroll
        for (int i = 0; i < 4; ++i) {
            const float4 wv = w[i];
            acc[4 * i + 0] = fmaf(ak, wv.x, acc[4 * i + 0]);
            acc[4 * i + 1] = fmaf(ak, wv.y, acc[4 * i + 1]);
            acc[4 * i + 2] = fmaf(ak, wv.z, acc[4 * i + 2]);
            acc[4 * i + 3] = fmaf(ak, wv.w, acc[4 * i + 3]);
        }
    }
    if (node < n) {
        float* o = outp + (size_t)node * out_stride + j0;
#pragma unroll
        for (int i = 0; i < 4; ++i) {
            float4 r;
            if (TANH) {
                r = make_float4(tanh_fast(acc[4 * i]), tanh_fast(acc[4 * i + 1]),
                                tanh_fast(acc[4 * i + 2]), tanh_fast(acc[4 * i + 3]));
            } else {
                r = make_float4(acc[4 * i], acc[4 * i + 1], acc[4 * i + 2], acc[4 * i + 3]);
            }
            *reinterpret_cast<float4*>(o + 4 * i) = r;
        }
    }
}

// ---------------- launch ----------------
extern "C" void kernel_launch(void* const* d_in, const int* in_sizes, int n_in,
                              void* d_out, int out_size, void* d_ws, size_t ws_size,
                              hipStream_t stream) {
    const float* X     = (const float*)d_in[0];
    const float* imp   = (const float*)d_in[1];
    const int*   ei    = (const int*)d_in[2];
    const float* gamma = (const float*)d_in[3];
    const float* beta  = (const float*)d_in[4];
    const float* W1 = (const float*)d_in[5];
    const float* b1 = (const float*)d_in[6];
    const float* W2 = (const float*)d_in[7];
    const float* b2 = (const float*)d_in[8];
    const float* W3 = (const float*)d_in[9];
    const float* b3 = (const float*)d_in[10];
    const float* W4 = (const float*)d_in[11];
    const float* b4 = (const float*)d_in[12];
    const float* W5 = (const float*)d_in[13];
    const float* b5 = (const float*)d_in[14];
    const float* Wf = (const float*)d_in[15];
    float* out = (float*)d_out;

    const int n = in_sizes[1];        // N
    const int e = in_sizes[2] / 2;    // E
    const int* src = ei;
    const int* dst = ei + e;

    // workspace carve (256B aligned)
    char* p = (char*)d_ws;
    auto carve = [&](size_t bytes) { char* r = p; p += (bytes + 255) & ~(size_t)255; return r; };
    int*   deg    = (int*)carve((size_t)n * sizeof(int));
    int*   rowptr = (int*)carve((size_t)(n + 1) * sizeof(int));
    int*   cursor = (int*)carve((size_t)n * sizeof(int));
    int*   csr    = (int*)carve((size_t)e * sizeof(int));
    const int nchunks = (n + SCAN_CHUNK - 1) / SCAN_CHUNK;
    int*   part   = (int*)carve((size_t)nchunks * sizeof(int));
    const int STATS_B = 256;
    float* ps    = (float*)carve((size_t)STATS_B * 128 * sizeof(float));
    float* pq    = (float*)carve((size_t)STATS_B * 128 * sizeof(float));
    float* scale = (float*)carve(128 * sizeof(float));
    float* shift = (float*)carve(128 * sizeof(float));
    float* VA    = (float*)carve((size_t)n * 64 * sizeof(float));
    float* VB    = (float*)carve((size_t)n * 64 * sizeof(float));

    const int ntiles = (n + 63) / 64;
    const int ngather = (n + 3) / 4;

    // BN stats
    k_stats<<<STATS_B, 128, 0, stream>>>(X, imp, ps, pq, n);
    k_finalize<<<1, 128, 0, stream>>>(ps, pq, gamma, beta, scale, shift, STATS_B, 1.0f / (float)n);

    // CSR build (by destination): csr[p] = src, sorted by dst
    hipMemsetAsync(deg, 0, (size_t)n * sizeof(int), stream);
    k_hist<<<1024, 256, 0, stream>>>(dst, deg, e);
    k_chunk_sum<<<nchunks, SCAN_T, 0, stream>>>(deg, part, n);
    k_scan_part<<<1, 128, 0, stream>>>(part, nchunks, rowptr + n);
    k_chunk_scan<<<nchunks, SCAN_T, 0, stream>>>(deg, part, rowptr, cursor, n);
    k_scatter<<<1024, 256, 0, stream>>>(src, dst, cursor, csr, e);

    // V1 = BN(X*imp) @ W1
    k_pregemm<<<ntiles, 256, 0, stream>>>(X, imp, scale, shift, W1, VA, n);

    // layer l: h_l = tanh(V_self + sum V_j + b_l) -> out slice; V_{l+1} = h_l @ W_{l+1}
    k_gather<<<ngather, 256, 0, stream>>>(VA, b1, out + 0,   rowptr, csr, n);
    k_dense<false><<<ntiles, 256, 0, stream>>>(out + 0,   384, W2, VB, 64, n);
    k_gather<<<ngather, 256, 0, stream>>>(VB, b2, out + 64,  rowptr, csr, n);
    k_dense<false><<<ntiles, 256, 0, stream>>>(out + 64,  384, W3, VA, 64, n);
    k_gather<<<ngather, 256, 0, stream>>>(VA, b3, out + 128, rowptr, csr, n);
    k_dense<false><<<ntiles, 256, 0, stream>>>(out + 128, 384, W4, VB, 64, n);
    k_gather<<<ngather, 256, 0, stream>>>(VB, b4, out + 192, rowptr, csr, n);
    k_dense<false><<<ntiles, 256, 0, stream>>>(out + 192, 384, W5, VA, 64, n);
    k_gather<<<ngather, 256, 0, stream>>>(VA, b5, out + 256, rowptr, csr, n);
    k_dense<true ><<<ntiles, 256, 0, stream>>>(out + 256, 384, Wf, out + 320, 384, n);
}

// Round 5
// 737.134 us; speedup vs baseline: 4.7344x; 1.1735x over previous
//
#include <hip/hip_runtime.h>
#include <cstdint>
#include <cstddef>

#define BN_EPS 1e-5f
#define SCAN_T 256
#define SCAN_CHUNK 1024
#define STATS_B 1024

__device__ __forceinline__ float tanh_fast(float x) {
    // tanh(x) = 1 - 2/(e^{2x}+1); exp overflow/underflow saturate correctly
    const float e = __expf(2.f * x);
    return 1.f - 2.f / (e + 1.f);
}

// ---------------- BN stats: vectorized, high-occupancy ----------------
// 1024 blocks x 256 threads; thread owns 4 channels (float4), 8 rows per block-iter.
__global__ __launch_bounds__(256) void k_stats(
        const float* __restrict__ X, const float* __restrict__ imp,
        float* __restrict__ ps, float* __restrict__ pq, int n) {
    __shared__ float sm[2][8][128];
    const int t = threadIdx.x;
    const int slot = t >> 5;          // 0..7 (row slot)
    const int g4 = (t & 31) << 2;     // channel group base
    float4 s = make_float4(0.f, 0.f, 0.f, 0.f);
    float4 q = make_float4(0.f, 0.f, 0.f, 0.f);
    for (int r = blockIdx.x * 8 + slot; r < n; r += gridDim.x * 8) {
        const float im = imp[r];
        const float4 x = *reinterpret_cast<const float4*>(X + (size_t)r * 128 + g4);
        const float vx = x.x * im, vy = x.y * im, vz = x.z * im, vw = x.w * im;
        s.x += vx; s.y += vy; s.z += vz; s.w += vw;
        q.x = fmaf(vx, vx, q.x); q.y = fmaf(vy, vy, q.y);
        q.z = fmaf(vz, vz, q.z); q.w = fmaf(vw, vw, q.w);
    }
    sm[0][slot][g4 + 0] = s.x; sm[0][slot][g4 + 1] = s.y;
    sm[0][slot][g4 + 2] = s.z; sm[0][slot][g4 + 3] = s.w;
    sm[1][slot][g4 + 0] = q.x; sm[1][slot][g4 + 1] = q.y;
    sm[1][slot][g4 + 2] = q.z; sm[1][slot][g4 + 3] = q.w;
    __syncthreads();
    if (t < 128) {
        float ss = 0.f, qq = 0.f;
#pragma unroll
        for (int sl = 0; sl < 8; ++sl) { ss += sm[0][sl][t]; qq += sm[1][sl][t]; }
        ps[blockIdx.x * 128 + t] = ss;
        pq[blockIdx.x * 128 + t] = qq;
    }
}

// 1 block x 1024 threads: 8 partial-lanes x 128 channels, LDS reduce.
__global__ __launch_bounds__(1024) void k_finalize(
        const float* __restrict__ ps, const float* __restrict__ pq,
        const float* __restrict__ gamma, const float* __restrict__ beta,
        float* __restrict__ scale, float* __restrict__ shift,
        int nblocks, float inv_n) {
    __shared__ float sm[2][8][128];
    const int t = threadIdx.x;
    const int part = t >> 7;          // 0..7
    const int c = t & 127;
    float s = 0.f, q = 0.f;
    for (int b = part; b < nblocks; b += 8) { s += ps[b * 128 + c]; q += pq[b * 128 + c]; }
    sm[0][part][c] = s; sm[1][part][c] = q;
    __syncthreads();
    if (t < 128) {
        float ss = 0.f, qq = 0.f;
#pragma unroll
        for (int p2 = 0; p2 < 8; ++p2) { ss += sm[0][p2][t]; qq += sm[1][p2][t]; }
        const float mu  = ss * inv_n;
        const float var = fmaf(-mu, mu, qq * inv_n);   // biased variance
        const float rs  = rsqrtf(var + BN_EPS);
        const float sc  = gamma[t] * rs;
        scale[t] = sc;
        shift[t] = fmaf(-mu, sc, beta[t]);
    }
}

// ---------------- CSR-by-destination build ----------------
__global__ void k_hist(const int* __restrict__ dst, int* __restrict__ deg, int e) {
    int i = blockIdx.x * blockDim.x + threadIdx.x;
    const int stride = gridDim.x * blockDim.x;
    for (; i < e; i += stride) atomicAdd(&deg[dst[i]], 1);
}

__global__ void k_chunk_sum(const int* __restrict__ deg, int* __restrict__ part, int n) {
    __shared__ int sm[SCAN_T];
    const int t = threadIdx.x;
    const int base = blockIdx.x * SCAN_CHUNK + t * 4;
    int s = 0;
#pragma unroll
    for (int j = 0; j < 4; ++j) { int idx = base + j; if (idx < n) s += deg[idx]; }
    sm[t] = s;
    __syncthreads();
    for (int off = SCAN_T / 2; off > 0; off >>= 1) {
        if (t < off) sm[t] += sm[t + off];
        __syncthreads();
    }
    if (t == 0) part[blockIdx.x] = sm[0];
}

__global__ void k_scan_part(int* __restrict__ part, int nparts, int* __restrict__ total_out) {
    __shared__ int sm[128];
    const int t = threadIdx.x;          // 128 threads
    int v = (t < nparts) ? part[t] : 0;
    const int mys = v;
    sm[t] = v;
    __syncthreads();
    for (int off = 1; off < 128; off <<= 1) {
        int u = (t >= off) ? sm[t - off] : 0;
        __syncthreads();
        sm[t] += u;
        __syncthreads();
    }
    if (t < nparts) part[t] = sm[t] - mys;
    if (t == 127) *total_out = sm[127];
}

__global__ void k_chunk_scan(const int* __restrict__ deg, const int* __restrict__ part,
                             int* __restrict__ rowptr, int* __restrict__ cursor, int n) {
    __shared__ int sm[SCAN_T];
    const int t = threadIdx.x;
    const int base = blockIdx.x * SCAN_CHUNK + t * 4;
    int l[4];
    int s = 0;
#pragma unroll
    for (int j = 0; j < 4; ++j) { int idx = base + j; l[j] = (idx < n) ? deg[idx] : 0; s += l[j]; }
    const int mys = s;
    sm[t] = s;
    __syncthreads();
    for (int off = 1; off < SCAN_T; off <<= 1) {
        int u = (t >= off) ? sm[t - off] : 0;
        __syncthreads();
        sm[t] += u;
        __syncthreads();
    }
    int excl = sm[t] - mys + part[blockIdx.x];
#pragma unroll
    for (int j = 0; j < 4; ++j) {
        int idx = base + j;
        if (idx < n) { rowptr[idx] = excl; cursor[idx] = excl; excl += l[j]; }
    }
}

__global__ void k_scatter(const int* __restrict__ src, const int* __restrict__ dst,
                          int* __restrict__ cursor, int* __restrict__ csr, int e) {
    int i = blockIdx.x * blockDim.x + threadIdx.x;
    const int stride = gridDim.x * blockDim.x;
    for (; i < e; i += stride) {
        const int p = atomicAdd(&cursor[dst[i]], 1);
        csr[p] = src[i];
    }
}

// ---------------- V1 = BN(X*imp) @ W1  (BN-apply fused, 128->64) ----------------
__global__ __launch_bounds__(256) void k_pregemm(
        const float* __restrict__ X, const float* __restrict__ imp,
        const float* __restrict__ scale, const float* __restrict__ shift,
        const float* __restrict__ W1, float* __restrict__ V1, int n) {
    __shared__ float tile[64 * 129];
    __shared__ float Wl[128 * 64];
    const int t = threadIdx.x;
    for (int i = t; i < 128 * 64 / 4; i += 256)
        reinterpret_cast<float4*>(Wl)[i] = reinterpret_cast<const float4*>(W1)[i];

    const int nodeL = t >> 2, q = t & 3;
    const int node = blockIdx.x * 64 + nodeL;
    if (node < n) {
        const float im = imp[node];
#pragma unroll
        for (int j = 0; j < 8; ++j) {
            const int c = q * 4 + j * 16;
            const float4 x  = *reinterpret_cast<const float4*>(X + (size_t)node * 128 + c);
            const float4 sc = *reinterpret_cast<const float4*>(scale + c);
            const float4 sh = *reinterpret_cast<const float4*>(shift + c);
            float* tr = tile + nodeL * 129 + c;
            tr[0] = fmaf(x.x * im, sc.x, sh.x);
            tr[1] = fmaf(x.y * im, sc.y, sh.y);
            tr[2] = fmaf(x.z * im, sc.z, sh.z);
            tr[3] = fmaf(x.w * im, sc.w, sh.w);
        }
    } else {
#pragma unroll
        for (int j = 0; j < 8; ++j) {
            const int c = q * 4 + j * 16;
            float* tr = tile + nodeL * 129 + c;
            tr[0] = 0.f; tr[1] = 0.f; tr[2] = 0.f; tr[3] = 0.f;
        }
    }
    __syncthreads();

    const int j0 = q * 16;
    float acc[16];
#pragma unroll
    for (int i = 0; i < 16; ++i) acc[i] = 0.f;
#pragma unroll 4
    for (int k = 0; k < 128; ++k) {
        const float ak = tile[nodeL * 129 + k];
        const float4* w = reinterpret_cast<const float4*>(Wl + k * 64 + j0);
#pragma unroll
        for (int i = 0; i < 4; ++i) {
            const float4 wv = w[i];
            acc[4 * i + 0] = fmaf(ak, wv.x, acc[4 * i + 0]);
            acc[4 * i + 1] = fmaf(ak, wv.y, acc[4 * i + 1]);
            acc[4 * i + 2] = fmaf(ak, wv.z, acc[4 * i + 2]);
            acc[4 * i + 3] = fmaf(ak, wv.w, acc[4 * i + 3]);
        }
    }
    if (node < n) {
        float* o = V1 + (size_t)node * 64 + j0;
#pragma unroll
        for (int i = 0; i < 4; ++i)
            *reinterpret_cast<float4*>(o + 4 * i) =
                make_float4(acc[4 * i], acc[4 * i + 1], acc[4 * i + 2], acc[4 * i + 3]);
    }
}

// ---------------- gather: h = tanh(V_self + sum_j V_j + b), register-only ----------------
__global__ __launch_bounds__(256, 8) void k_gather(
        const float* __restrict__ Vin, const float* __restrict__ bias,
        float* __restrict__ outh,    // d_out + col, row stride 384
        const int* __restrict__ rowptr, const int* __restrict__ csr, int n) {
    const int lane = threadIdx.x & 63;
    const int grp  = lane >> 4;
    const int gl4  = (lane & 15) << 2;
    const int w = blockIdx.x * 4 + (threadIdx.x >> 6);
    if (w >= n) return;

    float4 acc = make_float4(0.f, 0.f, 0.f, 0.f);
    if (grp == 0)
        acc = *reinterpret_cast<const float4*>(Vin + (size_t)w * 64 + gl4);

    const int beg = rowptr[w], end = rowptr[w + 1];
    int p = beg + grp;
    for (; p + 12 < end; p += 16) {          // 4 edges for this group (stride 4)
        const int s0 = csr[p];
        const int s1 = csr[p + 4];
        const int s2 = csr[p + 8];
        const int s3 = csr[p + 12];
        const float4 v0 = *reinterpret_cast<const float4*>(Vin + (size_t)s0 * 64 + gl4);
        const float4 v1 = *reinterpret_cast<const float4*>(Vin + (size_t)s1 * 64 + gl4);
        const float4 v2 = *reinterpret_cast<const float4*>(Vin + (size_t)s2 * 64 + gl4);
        const float4 v3 = *reinterpret_cast<const float4*>(Vin + (size_t)s3 * 64 + gl4);
        acc.x += v0.x + v1.x + v2.x + v3.x;
        acc.y += v0.y + v1.y + v2.y + v3.y;
        acc.z += v0.z + v1.z + v2.z + v3.z;
        acc.w += v0.w + v1.w + v2.w + v3.w;
    }
    for (; p < end; p += 4) {
        const int s = csr[p];
        const float4 v = *reinterpret_cast<const float4*>(Vin + (size_t)s * 64 + gl4);
        acc.x += v.x; acc.y += v.y; acc.z += v.z; acc.w += v.w;
    }

    // combine the 4 group partials
    acc.x += __shfl_xor(acc.x, 16); acc.y += __shfl_xor(acc.y, 16);
    acc.z += __shfl_xor(acc.z, 16); acc.w += __shfl_xor(acc.w, 16);
    acc.x += __shfl_xor(acc.x, 32); acc.y += __shfl_xor(acc.y, 32);
    acc.z += __shfl_xor(acc.z, 32); acc.w += __shfl_xor(acc.w, 32);

    if (grp == 0) {
        const float4 bb = *reinterpret_cast<const float4*>(bias + gl4);
        float4 r;
        r.x = tanh_fast(acc.x + bb.x);
        r.y = tanh_fast(acc.y + bb.y);
        r.z = tanh_fast(acc.z + bb.z);
        r.w = tanh_fast(acc.w + bb.w);
        *reinterpret_cast<float4*>(outh + (size_t)w * 384 + gl4) = r;
    }
}

// ---------------- dense: out = hin @ W  (optionally tanh) ----------------
template <bool TANH>
__global__ __launch_bounds__(256) void k_dense(
        const float* __restrict__ hin, int in_stride,
        const float* __restrict__ W,
        float* __restrict__ outp, int out_stride, int n) {
    __shared__ float tile[64 * 65];
    __shared__ float Wl[64 * 64];
    const int t = threadIdx.x;
    for (int i = t; i < 64 * 64 / 4; i += 256)
        reinterpret_cast<float4*>(Wl)[i] = reinterpret_cast<const float4*>(W)[i];

    const int nodeL = t >> 2, q = t & 3;
    const int node = blockIdx.x * 64 + nodeL;
    if (node < n) {
#pragma unroll
        for (int i = 0; i < 4; ++i) {
            const float4 v = *reinterpret_cast<const float4*>(hin + (size_t)node * in_stride + q * 16 + 4 * i);
            float* tr = tile + nodeL * 65 + q * 16 + 4 * i;
            tr[0] = v.x; tr[1] = v.y; tr[2] = v.z; tr[3] = v.w;
        }
    } else {
#pragma unroll
        for (int i = 0; i < 16; ++i) tile[nodeL * 65 + q * 16 + i] = 0.f;
    }
    __syncthreads();

    const int j0 = q * 16;
    float acc[16];
#pragma unroll
    for (int i = 0; i < 16; ++i) acc[i] = 0.f;
#pragma unroll 4
    for (int k = 0; k < 64; ++k) {
        const float ak = tile[nodeL * 65 + k];
        const float4* w = reinterpret_cast<const float4*>(Wl + k * 64 + j0);
#pragma unroll
        for (int i = 0; i < 4; ++i) {
            const float4 wv = w[i];
            acc[4 * i + 0] = fmaf(ak, wv.x, acc[4 * i + 0]);
            acc[4 * i + 1] = fmaf(ak, wv.y, acc[4 * i + 1]);
            acc[4 * i + 2] = fmaf(ak, wv.z, acc[4 * i + 2]);
            acc[4 * i + 3] = fmaf(ak, wv.w, acc[4 * i + 3]);
        }
    }
    if (node < n) {
        float* o = outp + (size_t)node * out_stride + j0;
#pragma unroll
        for (int i = 0; i < 4; ++i) {
            float4 r;
            if (TANH) {
                r = make_float4(tanh_fast(acc[4 * i]), tanh_fast(acc[4 * i + 1]),
                                tanh_fast(acc[4 * i + 2]), tanh_fast(acc[4 * i + 3]));
            } else {
                r = make_float4(acc[4 * i], acc[4 * i + 1], acc[4 * i + 2], acc[4 * i + 3]);
            }
            *reinterpret_cast<float4*>(o + 4 * i) = r;
        }
    }
}

// ---------------- launch ----------------
extern "C" void kernel_launch(void* const* d_in, const int* in_sizes, int n_in,
                              void* d_out, int out_size, void* d_ws, size_t ws_size,
                              hipStream_t stream) {
    const float* X     = (const float*)d_in[0];
    const float* imp   = (const float*)d_in[1];
    const int*   ei    = (const int*)d_in[2];
    const float* gamma = (const float*)d_in[3];
    const float* beta  = (const float*)d_in[4];
    const float* W1 = (const float*)d_in[5];
    const float* b1 = (const float*)d_in[6];
    const float* W2 = (const float*)d_in[7];
    const float* b2 = (const float*)d_in[8];
    const float* W3 = (const float*)d_in[9];
    const float* b3 = (const float*)d_in[10];
    const float* W4 = (const float*)d_in[11];
    const float* b4 = (const float*)d_in[12];
    const float* W5 = (const float*)d_in[13];
    const float* b5 = (const float*)d_in[14];
    const float* Wf = (const float*)d_in[15];
    float* out = (float*)d_out;

    const int n = in_sizes[1];        // N
    const int e = in_sizes[2] / 2;    // E
    const int* src = ei;
    const int* dst = ei + e;

    // workspace carve (256B aligned)
    char* p = (char*)d_ws;
    auto carve = [&](size_t bytes) { char* r = p; p += (bytes + 255) & ~(size_t)255; return r; };
    int*   deg    = (int*)carve((size_t)n * sizeof(int));
    int*   rowptr = (int*)carve((size_t)(n + 1) * sizeof(int));
    int*   cursor = (int*)carve((size_t)n * sizeof(int));
    int*   csr    = (int*)carve((size_t)e * sizeof(int));
    const int nchunks = (n + SCAN_CHUNK - 1) / SCAN_CHUNK;
    int*   part   = (int*)carve((size_t)nchunks * sizeof(int));
    float* ps    = (float*)carve((size_t)STATS_B * 128 * sizeof(float));
    float* pq    = (float*)carve((size_t)STATS_B * 128 * sizeof(float));
    float* scale = (float*)carve(128 * sizeof(float));
    float* shift = (float*)carve(128 * sizeof(float));
    float* VA    = (float*)carve((size_t)n * 64 * sizeof(float));
    float* VB    = (float*)carve((size_t)n * 64 * sizeof(float));

    const int ntiles = (n + 63) / 64;
    const int ngather = (n + 3) / 4;

    // BN stats
    k_stats<<<STATS_B, 256, 0, stream>>>(X, imp, ps, pq, n);
    k_finalize<<<1, 1024, 0, stream>>>(ps, pq, gamma, beta, scale, shift, STATS_B, 1.0f / (float)n);

    // CSR build (by destination): csr[p] = src, sorted by dst
    hipMemsetAsync(deg, 0, (size_t)n * sizeof(int), stream);
    k_hist<<<2048, 256, 0, stream>>>(dst, deg, e);
    k_chunk_sum<<<nchunks, SCAN_T, 0, stream>>>(deg, part, n);
    k_scan_part<<<1, 128, 0, stream>>>(part, nchunks, rowptr + n);
    k_chunk_scan<<<nchunks, SCAN_T, 0, stream>>>(deg, part, rowptr, cursor, n);
    k_scatter<<<2048, 256, 0, stream>>>(src, dst, cursor, csr, e);

    // V1 = BN(X*imp) @ W1
    k_pregemm<<<ntiles, 256, 0, stream>>>(X, imp, scale, shift, W1, VA, n);

    // layer l: h_l = tanh(V_self + sum V_j + b_l) -> out slice; V_{l+1} = h_l @ W_{l+1}
    k_gather<<<ngather, 256, 0, stream>>>(VA, b1, out + 0,   rowptr, csr, n);
    k_dense<false><<<ntiles, 256, 0, stream>>>(out + 0,   384, W2, VB, 64, n);
    k_gather<<<ngather, 256, 0, stream>>>(VB, b2, out + 64,  rowptr, csr, n);
    k_dense<false><<<ntiles, 256, 0, stream>>>(out + 64,  384, W3, VA, 64, n);
    k_gather<<<ngather, 256, 0, stream>>>(VA, b3, out + 128, rowptr, csr, n);
    k_dense<false><<<ntiles, 256, 0, stream>>>(out + 128, 384, W4, VB, 64, n);
    k_gather<<<ngather, 256, 0, stream>>>(VB, b4, out + 192, rowptr, csr, n);
    k_dense<false><<<ntiles, 256, 0, stream>>>(out + 192, 384, W5, VA, 64, n);
    k_gather<<<ngather, 256, 0, stream>>>(VA, b5, out + 256, rowptr, csr, n);
    k_dense<true ><<<ntiles, 256, 0, stream>>>(out + 256, 384, Wf, out + 320, 384, n);
}

// Round 6
// 573.040 us; speedup vs baseline: 6.0901x; 1.2864x over previous
//
#include <hip/hip_runtime.h>
#include <cstdint>
#include <cstddef>

#define BN_EPS 1e-5f
#define STATS_B 1024

// bucket sort params: 256 nodes/bucket, supports n <= 131072
#define NPB_SHIFT 8
#define NPB 256
#define MAXNB 512
#define P1B 256
#define P2CAP 8192

__device__ __forceinline__ float tanh_fast(float x) {
    const float e = __expf(2.f * x);
    return 1.f - 2.f / (e + 1.f);
}

// ---------------- BN stats: vectorized, high-occupancy ----------------
__global__ __launch_bounds__(256) void k_stats(
        const float* __restrict__ X, const float* __restrict__ imp,
        float* __restrict__ ps, float* __restrict__ pq, int n) {
    __shared__ float sm[2][8][128];
    const int t = threadIdx.x;
    const int slot = t >> 5;
    const int g4 = (t & 31) << 2;
    float4 s = make_float4(0.f, 0.f, 0.f, 0.f);
    float4 q = make_float4(0.f, 0.f, 0.f, 0.f);
    for (int r = blockIdx.x * 8 + slot; r < n; r += gridDim.x * 8) {
        const float im = imp[r];
        const float4 x = *reinterpret_cast<const float4*>(X + (size_t)r * 128 + g4);
        const float vx = x.x * im, vy = x.y * im, vz = x.z * im, vw = x.w * im;
        s.x += vx; s.y += vy; s.z += vz; s.w += vw;
        q.x = fmaf(vx, vx, q.x); q.y = fmaf(vy, vy, q.y);
        q.z = fmaf(vz, vz, q.z); q.w = fmaf(vw, vw, q.w);
    }
    sm[0][slot][g4 + 0] = s.x; sm[0][slot][g4 + 1] = s.y;
    sm[0][slot][g4 + 2] = s.z; sm[0][slot][g4 + 3] = s.w;
    sm[1][slot][g4 + 0] = q.x; sm[1][slot][g4 + 1] = q.y;
    sm[1][slot][g4 + 2] = q.z; sm[1][slot][g4 + 3] = q.w;
    __syncthreads();
    if (t < 128) {
        float ss = 0.f, qq = 0.f;
#pragma unroll
        for (int sl = 0; sl < 8; ++sl) { ss += sm[0][sl][t]; qq += sm[1][sl][t]; }
        ps[blockIdx.x * 128 + t] = ss;
        pq[blockIdx.x * 128 + t] = qq;
    }
}

__global__ __launch_bounds__(1024) void k_finalize(
        const float* __restrict__ ps, const float* __restrict__ pq,
        const float* __restrict__ gamma, const float* __restrict__ beta,
        float* __restrict__ scale, float* __restrict__ shift,
        int nblocks, float inv_n) {
    __shared__ float sm[2][8][128];
    const int t = threadIdx.x;
    const int part = t >> 7;
    const int c = t & 127;
    float s = 0.f, q = 0.f;
    for (int b = part; b < nblocks; b += 8) { s += ps[b * 128 + c]; q += pq[b * 128 + c]; }
    sm[0][part][c] = s; sm[1][part][c] = q;
    __syncthreads();
    if (t < 128) {
        float ss = 0.f, qq = 0.f;
#pragma unroll
        for (int p2 = 0; p2 < 8; ++p2) { ss += sm[0][p2][t]; qq += sm[1][p2][t]; }
        const float mu  = ss * inv_n;
        const float var = fmaf(-mu, mu, qq * inv_n);
        const float rs  = rsqrtf(var + BN_EPS);
        const float sc  = gamma[t] * rs;
        scale[t] = sc;
        shift[t] = fmaf(-mu, sc, beta[t]);
    }
}

// ---------------- atomic-free CSR build: two-level counting sort ----------------
// pass 1a: per-block LDS histogram over buckets (bucket = dst >> NPB_SHIFT)
__global__ __launch_bounds__(256) void k_p1cnt(
        const int* __restrict__ dst, int* __restrict__ gh,
        int e, int nb, int chunk) {
    __shared__ int h[MAXNB];
    const int t = threadIdx.x;
    for (int i = t; i < nb; i += 256) h[i] = 0;
    __syncthreads();
    const int beg = blockIdx.x * chunk;
    const int end = (beg + chunk < e) ? beg + chunk : e;
    if (beg < e) {
        if ((e & 3) == 0) {
            const int nv = (end - beg) >> 2;
            const int4* d4p = reinterpret_cast<const int4*>(dst + beg);
            for (int i = t; i < nv; i += 256) {
                const int4 d = d4p[i];
                atomicAdd(&h[d.x >> NPB_SHIFT], 1);
                atomicAdd(&h[d.y >> NPB_SHIFT], 1);
                atomicAdd(&h[d.z >> NPB_SHIFT], 1);
                atomicAdd(&h[d.w >> NPB_SHIFT], 1);
            }
            for (int i = beg + (nv << 2) + t; i < end; i += 256)
                atomicAdd(&h[dst[i] >> NPB_SHIFT], 1);
        } else {
            for (int i = beg + t; i < end; i += 256)
                atomicAdd(&h[dst[i] >> NPB_SHIFT], 1);
        }
    }
    __syncthreads();
    for (int i = t; i < nb; i += 256) gh[blockIdx.x * MAXNB + i] = h[i];
}

// pass 1b: one block; bucket bases + per-(block,bucket) positions (gh rewritten in place)
__global__ __launch_bounds__(MAXNB) void k_p1scan(
        int* __restrict__ gh, int* __restrict__ bb, int e, int nb) {
    __shared__ int sm[MAXNB];
    const int t = threadIdx.x;
    int tot = 0;
    if (t < nb)
        for (int b = 0; b < P1B; ++b) tot += gh[b * MAXNB + t];
    sm[t] = (t < nb) ? tot : 0;
    __syncthreads();
    for (int off = 1; off < MAXNB; off <<= 1) {
        int u = (t >= off) ? sm[t - off] : 0;
        __syncthreads();
        sm[t] += u;
        __syncthreads();
    }
    const int excl = sm[t] - ((t < nb) ? tot : 0);
    if (t < nb) {
        bb[t] = excl;
        int run = excl;
        for (int b = 0; b < P1B; ++b) {
            const int idx = b * MAXNB + t;
            const int tmp = gh[idx];
            gh[idx] = run;
            run += tmp;
        }
    }
    if (t == 0) bb[nb] = e;
}

// pass 1c: place (src,dst) into bucket-ordered ebuf via LDS cursors (no global atomics)
__global__ __launch_bounds__(256) void k_p1scat(
        const int* __restrict__ src, const int* __restrict__ dst,
        const int* __restrict__ gh, int2* __restrict__ ebuf,
        int e, int nb, int chunk) {
    __shared__ int cur[MAXNB];
    const int t = threadIdx.x;
    for (int i = t; i < nb; i += 256) cur[i] = gh[blockIdx.x * MAXNB + i];
    __syncthreads();
    const int beg = blockIdx.x * chunk;
    const int end = (beg + chunk < e) ? beg + chunk : e;
    if (beg < e) {
        if ((e & 3) == 0) {
            const int nv = (end - beg) >> 2;
            const int4* d4p = reinterpret_cast<const int4*>(dst + beg);
            const int4* s4p = reinterpret_cast<const int4*>(src + beg);
            for (int i = t; i < nv; i += 256) {
                const int4 d = d4p[i];
                const int4 s = s4p[i];
                int q;
                q = atomicAdd(&cur[d.x >> NPB_SHIFT], 1); ebuf[q] = make_int2(s.x, d.x);
                q = atomicAdd(&cur[d.y >> NPB_SHIFT], 1); ebuf[q] = make_int2(s.y, d.y);
                q = atomicAdd(&cur[d.z >> NPB_SHIFT], 1); ebuf[q] = make_int2(s.z, d.z);
                q = atomicAdd(&cur[d.w >> NPB_SHIFT], 1); ebuf[q] = make_int2(s.w, d.w);
            }
            for (int i = beg + (nv << 2) + t; i < end; i += 256) {
                const int d = dst[i];
                const int q = atomicAdd(&cur[d >> NPB_SHIFT], 1);
                ebuf[q] = make_int2(src[i], d);
            }
        } else {
            for (int i = beg + t; i < end; i += 256) {
                const int d = dst[i];
                const int q = atomicAdd(&cur[d >> NPB_SHIFT], 1);
                ebuf[q] = make_int2(src[i], d);
            }
        }
    }
}

// pass 2: one block per bucket — exact sort by dst in LDS, coalesced csr/rowptr writes
__global__ __launch_bounds__(256) void k_p2(
        const int2* __restrict__ ebuf, const int* __restrict__ bb,
        int* __restrict__ rowptr, int* __restrict__ csr, int* __restrict__ gcur,
        int n, int nb) {
    __shared__ int lout[P2CAP];
    __shared__ int hc[NPB];
    __shared__ int sc[NPB];
    const int b = blockIdx.x;
    const int t = threadIdx.x;
    const int nodeBase = b << NPB_SHIFT;
    const int nEnd = (nodeBase + NPB < n) ? nodeBase + NPB : n;
    const int nloc = nEnd - nodeBase;
    const int rbeg = bb[b], rend = bb[b + 1];
    const int cnt = rend - rbeg;

    hc[t] = 0;
    __syncthreads();
    for (int p = rbeg + t; p < rend; p += 256)
        atomicAdd(&hc[ebuf[p].y - nodeBase], 1);
    __syncthreads();

    // exclusive scan of 256 counters
    const int a = hc[t];
    sc[t] = a;
    __syncthreads();
    for (int off = 1; off < 256; off <<= 1) {
        int u = (t >= off) ? sc[t - off] : 0;
        __syncthreads();
        sc[t] += u;
        __syncthreads();
    }
    const int excl = sc[t] - a;
    if (t < nloc) rowptr[nodeBase + t] = rbeg + excl;
    if (b == nb - 1 && t == 0) rowptr[n] = rend;
    hc[t] = excl;            // becomes cursor
    __syncthreads();

    if (cnt <= P2CAP) {
        for (int p = rbeg + t; p < rend; p += 256) {
            const int2 sd = ebuf[p];
            const int q = atomicAdd(&hc[sd.y - nodeBase], 1);
            lout[q] = sd.x;
        }
        __syncthreads();
        for (int i = t; i < cnt; i += 256) csr[rbeg + i] = lout[i];
    } else {
        // overflow fallback (never expected for uniform input): global cursors
        if (t < nloc) gcur[nodeBase + t] = rbeg + excl;
        __syncthreads();
        for (int p = rbeg + t; p < rend; p += 256) {
            const int2 sd = ebuf[p];
            const int q = atomicAdd(&gcur[sd.y], 1);
            csr[q] = sd.x;
        }
    }
}

// ---------------- V1 = BN(X*imp) @ W1  (BN-apply fused, 128->64) ----------------
__global__ __launch_bounds__(256) void k_pregemm(
        const float* __restrict__ X, const float* __restrict__ imp,
        const float* __restrict__ scale, const float* __restrict__ shift,
        const float* __restrict__ W1, float* __restrict__ V1, int n) {
    __shared__ float tile[64 * 129];
    __shared__ float Wl[128 * 64];
    const int t = threadIdx.x;
    for (int i = t; i < 128 * 64 / 4; i += 256)
        reinterpret_cast<float4*>(Wl)[i] = reinterpret_cast<const float4*>(W1)[i];

    const int nodeL = t >> 2, q = t & 3;
    const int node = blockIdx.x * 64 + nodeL;
    if (node < n) {
        const float im = imp[node];
#pragma unroll
        for (int j = 0; j < 8; ++j) {
            const int c = q * 4 + j * 16;
            const float4 x  = *reinterpret_cast<const float4*>(X + (size_t)node * 128 + c);
            const float4 sc = *reinterpret_cast<const float4*>(scale + c);
            const float4 sh = *reinterpret_cast<const float4*>(shift + c);
            float* tr = tile + nodeL * 129 + c;
            tr[0] = fmaf(x.x * im, sc.x, sh.x);
            tr[1] = fmaf(x.y * im, sc.y, sh.y);
            tr[2] = fmaf(x.z * im, sc.z, sh.z);
            tr[3] = fmaf(x.w * im, sc.w, sh.w);
        }
    } else {
#pragma unroll
        for (int j = 0; j < 8; ++j) {
            const int c = q * 4 + j * 16;
            float* tr = tile + nodeL * 129 + c;
            tr[0] = 0.f; tr[1] = 0.f; tr[2] = 0.f; tr[3] = 0.f;
        }
    }
    __syncthreads();

    const int j0 = q * 16;
    float acc[16];
#pragma unroll
    for (int i = 0; i < 16; ++i) acc[i] = 0.f;
#pragma unroll 4
    for (int k = 0; k < 128; ++k) {
        const float ak = tile[nodeL * 129 + k];
        const float4* w = reinterpret_cast<const float4*>(Wl + k * 64 + j0);
#pragma unroll
        for (int i = 0; i < 4; ++i) {
            const float4 wv = w[i];
            acc[4 * i + 0] = fmaf(ak, wv.x, acc[4 * i + 0]);
            acc[4 * i + 1] = fmaf(ak, wv.y, acc[4 * i + 1]);
            acc[4 * i + 2] = fmaf(ak, wv.z, acc[4 * i + 2]);
            acc[4 * i + 3] = fmaf(ak, wv.w, acc[4 * i + 3]);
        }
    }
    if (node < n) {
        float* o = V1 + (size_t)node * 64 + j0;
#pragma unroll
        for (int i = 0; i < 4; ++i)
            *reinterpret_cast<float4*>(o + 4 * i) =
                make_float4(acc[4 * i], acc[4 * i + 1], acc[4 * i + 2], acc[4 * i + 3]);
    }
}

// ---------------- gather: h = tanh(V_self + sum_j V_j + b), register-only ----------------
__global__ __launch_bounds__(256, 8) void k_gather(
        const float* __restrict__ Vin, const float* __restrict__ bias,
        float* __restrict__ outh,    // d_out + col, row stride 384
        const int* __restrict__ rowptr, const int* __restrict__ csr, int n) {
    const int lane = threadIdx.x & 63;
    const int grp  = lane >> 4;
    const int gl4  = (lane & 15) << 2;
    const int w = blockIdx.x * 4 + (threadIdx.x >> 6);
    if (w >= n) return;

    float4 acc = make_float4(0.f, 0.f, 0.f, 0.f);
    if (grp == 0)
        acc = *reinterpret_cast<const float4*>(Vin + (size_t)w * 64 + gl4);

    const int beg = rowptr[w], end = rowptr[w + 1];
    int p = beg + grp;
    for (; p + 12 < end; p += 16) {
        const int s0 = csr[p];
        const int s1 = csr[p + 4];
        const int s2 = csr[p + 8];
        const int s3 = csr[p + 12];
        const float4 v0 = *reinterpret_cast<const float4*>(Vin + (size_t)s0 * 64 + gl4);
        const float4 v1 = *reinterpret_cast<const float4*>(Vin + (size_t)s1 * 64 + gl4);
        const float4 v2 = *reinterpret_cast<const float4*>(Vin + (size_t)s2 * 64 + gl4);
        const float4 v3 = *reinterpret_cast<const float4*>(Vin + (size_t)s3 * 64 + gl4);
        acc.x += v0.x + v1.x + v2.x + v3.x;
        acc.y += v0.y + v1.y + v2.y + v3.y;
        acc.z += v0.z + v1.z + v2.z + v3.z;
        acc.w += v0.w + v1.w + v2.w + v3.w;
    }
    for (; p < end; p += 4) {
        const int s = csr[p];
        const float4 v = *reinterpret_cast<const float4*>(Vin + (size_t)s * 64 + gl4);
        acc.x += v.x; acc.y += v.y; acc.z += v.z; acc.w += v.w;
    }

    acc.x += __shfl_xor(acc.x, 16); acc.y += __shfl_xor(acc.y, 16);
    acc.z += __shfl_xor(acc.z, 16); acc.w += __shfl_xor(acc.w, 16);
    acc.x += __shfl_xor(acc.x, 32); acc.y += __shfl_xor(acc.y, 32);
    acc.z += __shfl_xor(acc.z, 32); acc.w += __shfl_xor(acc.w, 32);

    if (grp == 0) {
        const float4 bb = *reinterpret_cast<const float4*>(bias + gl4);
        float4 r;
        r.x = tanh_fast(acc.x + bb.x);
        r.y = tanh_fast(acc.y + bb.y);
        r.z = tanh_fast(acc.z + bb.z);
        r.w = tanh_fast(acc.w + bb.w);
        *reinterpret_cast<float4*>(outh + (size_t)w * 384 + gl4) = r;
    }
}

// ---------------- dense: out = hin @ W  (optionally tanh) ----------------
template <bool TANH>
__global__ __launch_bounds__(256) void k_dense(
        const float* __restrict__ hin, int in_stride,
        const float* __restrict__ W,
        float* __restrict__ outp, int out_stride, int n) {
    __shared__ float tile[64 * 65];
    __shared__ float Wl[64 * 64];
    const int t = threadIdx.x;
    for (int i = t; i < 64 * 64 / 4; i += 256)
        reinterpret_cast<float4*>(Wl)[i] = reinterpret_cast<const float4*>(W)[i];

    const int nodeL = t >> 2, q = t & 3;
    const int node = blockIdx.x * 64 + nodeL;
    if (node < n) {
#pragma unroll
        for (int i = 0; i < 4; ++i) {
            const float4 v = *reinterpret_cast<const float4*>(hin + (size_t)node * in_stride + q * 16 + 4 * i);
            float* tr = tile + nodeL * 65 + q * 16 + 4 * i;
            tr[0] = v.x; tr[1] = v.y; tr[2] = v.z; tr[3] = v.w;
        }
    } else {
#pragma unroll
        for (int i = 0; i < 16; ++i) tile[nodeL * 65 + q * 16 + i] = 0.f;
    }
    __syncthreads();

    const int j0 = q * 16;
    float acc[16];
#pragma unroll
    for (int i = 0; i < 16; ++i) acc[i] = 0.f;
#pragma unroll 4
    for (int k = 0; k < 64; ++k) {
        const float ak = tile[nodeL * 65 + k];
        const float4* w = reinterpret_cast<const float4*>(Wl + k * 64 + j0);
#pragma unroll
        for (int i = 0; i < 4; ++i) {
            const float4 wv = w[i];
            acc[4 * i + 0] = fmaf(ak, wv.x, acc[4 * i + 0]);
            acc[4 * i + 1] = fmaf(ak, wv.y, acc[4 * i + 1]);
            acc[4 * i + 2] = fmaf(ak, wv.z, acc[4 * i + 2]);
            acc[4 * i + 3] = fmaf(ak, wv.w, acc[4 * i + 3]);
        }
    }
    if (node < n) {
        float* o = outp + (size_t)node * out_stride + j0;
#pragma unroll
        for (int i = 0; i < 4; ++i) {
            float4 r;
            if (TANH) {
                r = make_float4(tanh_fast(acc[4 * i]), tanh_fast(acc[4 * i + 1]),
                                tanh_fast(acc[4 * i + 2]), tanh_fast(acc[4 * i + 3]));
            } else {
                r = make_float4(acc[4 * i], acc[4 * i + 1], acc[4 * i + 2], acc[4 * i + 3]);
            }
            *reinterpret_cast<float4*>(o + 4 * i) = r;
        }
    }
}

// ---------------- launch ----------------
extern "C" void kernel_launch(void* const* d_in, const int* in_sizes, int n_in,
                              void* d_out, int out_size, void* d_ws, size_t ws_size,
                              hipStream_t stream) {
    const float* X     = (const float*)d_in[0];
    const float* imp   = (const float*)d_in[1];
    const int*   ei    = (const int*)d_in[2];
    const float* gamma = (const float*)d_in[3];
    const float* beta  = (const float*)d_in[4];
    const float* W1 = (const float*)d_in[5];
    const float* b1 = (const float*)d_in[6];
    const float* W2 = (const float*)d_in[7];
    const float* b2 = (const float*)d_in[8];
    const float* W3 = (const float*)d_in[9];
    const float* b3 = (const float*)d_in[10];
    const float* W4 = (const float*)d_in[11];
    const float* b4 = (const float*)d_in[12];
    const float* W5 = (const float*)d_in[13];
    const float* b5 = (const float*)d_in[14];
    const float* Wf = (const float*)d_in[15];
    float* out = (float*)d_out;

    const int n = in_sizes[1];        // N
    const int e = in_sizes[2] / 2;    // E
    const int* src = ei;
    const int* dst = ei + e;
    const int nb = (n + NPB - 1) >> NPB_SHIFT;          // buckets (<= MAXNB for n<=131072)
    const int chunk = (((e + P1B - 1) / P1B) + 3) & ~3; // pass-1 per-block edge chunk

    // workspace carve (256B aligned)
    char* p = (char*)d_ws;
    auto carve = [&](size_t bytes) { char* r = p; p += (bytes + 255) & ~(size_t)255; return r; };
    int*   gh     = (int*)carve((size_t)P1B * MAXNB * sizeof(int));
    int*   bb     = (int*)carve((size_t)(MAXNB + 1) * sizeof(int));
    int*   rowptr = (int*)carve((size_t)(n + 1) * sizeof(int));
    int*   csr    = (int*)carve((size_t)e * sizeof(int));
    int*   gcur   = (int*)carve((size_t)n * sizeof(int));
    float* ps     = (float*)carve((size_t)STATS_B * 128 * sizeof(float));
    float* pq     = (float*)carve((size_t)STATS_B * 128 * sizeof(float));
    float* scale  = (float*)carve(128 * sizeof(float));
    float* shift  = (float*)carve(128 * sizeof(float));
    // VA/VB overlaid with ebuf (disjoint lifetimes: ebuf dead before k_pregemm writes VA)
    char*  uni    = carve(2 * (size_t)n * 64 * sizeof(float));
    float* VA     = (float*)uni;
    float* VB     = (float*)(uni + (size_t)n * 64 * sizeof(float));
    int2*  ebuf   = (int2*)uni;

    const int ntiles = (n + 63) / 64;
    const int ngather = (n + 3) / 4;

    // BN stats
    k_stats<<<STATS_B, 256, 0, stream>>>(X, imp, ps, pq, n);
    k_finalize<<<1, 1024, 0, stream>>>(ps, pq, gamma, beta, scale, shift, STATS_B, 1.0f / (float)n);

    // atomic-free CSR build (counting sort by destination)
    k_p1cnt<<<P1B, 256, 0, stream>>>(dst, gh, e, nb, chunk);
    k_p1scan<<<1, MAXNB, 0, stream>>>(gh, bb, e, nb);
    k_p1scat<<<P1B, 256, 0, stream>>>(src, dst, gh, ebuf, e, nb, chunk);
    k_p2<<<nb, 256, 0, stream>>>(ebuf, bb, rowptr, csr, gcur, n, nb);

    // V1 = BN(X*imp) @ W1
    k_pregemm<<<ntiles, 256, 0, stream>>>(X, imp, scale, shift, W1, VA, n);

    // layer l: h_l = tanh(V_self + sum V_j + b_l) -> out slice; V_{l+1} = h_l @ W_{l+1}
    k_gather<<<ngather, 256, 0, stream>>>(VA, b1, out + 0,   rowptr, csr, n);
    k_dense<false><<<ntiles, 256, 0, stream>>>(out + 0,   384, W2, VB, 64, n);
    k_gather<<<ngather, 256, 0, stream>>>(VB, b2, out + 64,  rowptr, csr, n);
    k_dense<false><<<ntiles, 256, 0, stream>>>(out + 64,  384, W3, VA, 64, n);
    k_gather<<<ngather, 256, 0, stream>>>(VA, b3, out + 128, rowptr, csr, n);
    k_dense<false><<<ntiles, 256, 0, stream>>>(out + 128, 384, W4, VB, 64, n);
    k_gather<<<ngather, 256, 0, stream>>>(VB, b4, out + 192, rowptr, csr, n);
    k_dense<false><<<ntiles, 256, 0, stream>>>(out + 192, 384, W5, VA, 64, n);
    k_gather<<<ngather, 256, 0, stream>>>(VA, b5, out + 256, rowptr, csr, n);
    k_dense<true ><<<ntiles, 256, 0, stream>>>(out + 256, 384, Wf, out + 320, 384, n);
}

// Round 7
// 507.508 us; speedup vs baseline: 6.8765x; 1.1291x over previous
//
#include <hip/hip_runtime.h>
#include <hip/hip_fp16.h>
#include <cstdint>
#include <cstddef>

#define BN_EPS 1e-5f
#define STATS_B 1024

// bucket sort params: 256 nodes/bucket, supports n <= 131072
#define NPB_SHIFT 8
#define NPB 256
#define MAXNB 512
#define P1B 256
#define P2CAP 8192

__device__ __forceinline__ float tanh_fast(float x) {
    const float e = __expf(2.f * x);
    return 1.f - 2.f / (e + 1.f);
}

__device__ __forceinline__ float4 h4_to_f4(uint2 u) {
    const __half2 h0 = *reinterpret_cast<__half2*>(&u.x);
    const __half2 h1 = *reinterpret_cast<__half2*>(&u.y);
    const float2 f0 = __half22float2(h0);
    const float2 f1 = __half22float2(h1);
    return make_float4(f0.x, f0.y, f1.x, f1.y);
}

__device__ __forceinline__ unsigned pk2(float a, float b) {
    __half2 h = __floats2half2_rn(a, b);
    return *reinterpret_cast<unsigned*>(&h);
}

// store 16 fp32 values as 16 fp16 (32B, two uint4 stores); o 16B-aligned
__device__ __forceinline__ void store_h16(__half* o, const float* a) {
    const uint4 u0 = make_uint4(pk2(a[0], a[1]),  pk2(a[2], a[3]),
                                pk2(a[4], a[5]),  pk2(a[6], a[7]));
    const uint4 u1 = make_uint4(pk2(a[8], a[9]),  pk2(a[10], a[11]),
                                pk2(a[12], a[13]), pk2(a[14], a[15]));
    *reinterpret_cast<uint4*>(o) = u0;
    *reinterpret_cast<uint4*>(o + 8) = u1;
}

// ---------------- BN stats: vectorized, high-occupancy ----------------
__global__ __launch_bounds__(256) void k_stats(
        const float* __restrict__ X, const float* __restrict__ imp,
        float* __restrict__ ps, float* __restrict__ pq, int n) {
    __shared__ float sm[2][8][128];
    const int t = threadIdx.x;
    const int slot = t >> 5;
    const int g4 = (t & 31) << 2;
    float4 s = make_float4(0.f, 0.f, 0.f, 0.f);
    float4 q = make_float4(0.f, 0.f, 0.f, 0.f);
    for (int r = blockIdx.x * 8 + slot; r < n; r += gridDim.x * 8) {
        const float im = imp[r];
        const float4 x = *reinterpret_cast<const float4*>(X + (size_t)r * 128 + g4);
        const float vx = x.x * im, vy = x.y * im, vz = x.z * im, vw = x.w * im;
        s.x += vx; s.y += vy; s.z += vz; s.w += vw;
        q.x = fmaf(vx, vx, q.x); q.y = fmaf(vy, vy, q.y);
        q.z = fmaf(vz, vz, q.z); q.w = fmaf(vw, vw, q.w);
    }
    sm[0][slot][g4 + 0] = s.x; sm[0][slot][g4 + 1] = s.y;
    sm[0][slot][g4 + 2] = s.z; sm[0][slot][g4 + 3] = s.w;
    sm[1][slot][g4 + 0] = q.x; sm[1][slot][g4 + 1] = q.y;
    sm[1][slot][g4 + 2] = q.z; sm[1][slot][g4 + 3] = q.w;
    __syncthreads();
    if (t < 128) {
        float ss = 0.f, qq = 0.f;
#pragma unroll
        for (int sl = 0; sl < 8; ++sl) { ss += sm[0][sl][t]; qq += sm[1][sl][t]; }
        ps[blockIdx.x * 128 + t] = ss;
        pq[blockIdx.x * 128 + t] = qq;
    }
}

__global__ __launch_bounds__(1024) void k_finalize(
        const float* __restrict__ ps, const float* __restrict__ pq,
        const float* __restrict__ gamma, const float* __restrict__ beta,
        float* __restrict__ scale, float* __restrict__ shift,
        int nblocks, float inv_n) {
    __shared__ float sm[2][8][128];
    const int t = threadIdx.x;
    const int part = t >> 7;
    const int c = t & 127;
    float s = 0.f, q = 0.f;
    for (int b = part; b < nblocks; b += 8) { s += ps[b * 128 + c]; q += pq[b * 128 + c]; }
    sm[0][part][c] = s; sm[1][part][c] = q;
    __syncthreads();
    if (t < 128) {
        float ss = 0.f, qq = 0.f;
#pragma unroll
        for (int p2 = 0; p2 < 8; ++p2) { ss += sm[0][p2][t]; qq += sm[1][p2][t]; }
        const float mu  = ss * inv_n;
        const float var = fmaf(-mu, mu, qq * inv_n);
        const float rs  = rsqrtf(var + BN_EPS);
        const float sc  = gamma[t] * rs;
        scale[t] = sc;
        shift[t] = fmaf(-mu, sc, beta[t]);
    }
}

// ---------------- atomic-free CSR build: two-level counting sort ----------------
__global__ __launch_bounds__(256) void k_p1cnt(
        const int* __restrict__ dst, int* __restrict__ gh,
        int e, int nb, int chunk) {
    __shared__ int h[MAXNB];
    const int t = threadIdx.x;
    for (int i = t; i < nb; i += 256) h[i] = 0;
    __syncthreads();
    const int beg = blockIdx.x * chunk;
    const int end = (beg + chunk < e) ? beg + chunk : e;
    if (beg < e) {
        if ((e & 3) == 0) {
            const int nv = (end - beg) >> 2;
            const int4* d4p = reinterpret_cast<const int4*>(dst + beg);
            for (int i = t; i < nv; i += 256) {
                const int4 d = d4p[i];
                atomicAdd(&h[d.x >> NPB_SHIFT], 1);
                atomicAdd(&h[d.y >> NPB_SHIFT], 1);
                atomicAdd(&h[d.z >> NPB_SHIFT], 1);
                atomicAdd(&h[d.w >> NPB_SHIFT], 1);
            }
            for (int i = beg + (nv << 2) + t; i < end; i += 256)
                atomicAdd(&h[dst[i] >> NPB_SHIFT], 1);
        } else {
            for (int i = beg + t; i < end; i += 256)
                atomicAdd(&h[dst[i] >> NPB_SHIFT], 1);
        }
    }
    __syncthreads();
    for (int i = t; i < nb; i += 256) gh[blockIdx.x * MAXNB + i] = h[i];
}

__global__ __launch_bounds__(MAXNB) void k_p1scan(
        int* __restrict__ gh, int* __restrict__ bb, int e, int nb) {
    __shared__ int sm[MAXNB];
    const int t = threadIdx.x;
    int tot = 0;
    if (t < nb)
        for (int b = 0; b < P1B; ++b) tot += gh[b * MAXNB + t];
    sm[t] = (t < nb) ? tot : 0;
    __syncthreads();
    for (int off = 1; off < MAXNB; off <<= 1) {
        int u = (t >= off) ? sm[t - off] : 0;
        __syncthreads();
        sm[t] += u;
        __syncthreads();
    }
    const int excl = sm[t] - ((t < nb) ? tot : 0);
    if (t < nb) {
        bb[t] = excl;
        int run = excl;
        for (int b = 0; b < P1B; ++b) {
            const int idx = b * MAXNB + t;
            const int tmp = gh[idx];
            gh[idx] = run;
            run += tmp;
        }
    }
    if (t == 0) bb[nb] = e;
}

__global__ __launch_bounds__(256) void k_p1scat(
        const int* __restrict__ src, const int* __restrict__ dst,
        const int* __restrict__ gh, int2* __restrict__ ebuf,
        int e, int nb, int chunk) {
    __shared__ int cur[MAXNB];
    const int t = threadIdx.x;
    for (int i = t; i < nb; i += 256) cur[i] = gh[blockIdx.x * MAXNB + i];
    __syncthreads();
    const int beg = blockIdx.x * chunk;
    const int end = (beg + chunk < e) ? beg + chunk : e;
    if (beg < e) {
        if ((e & 3) == 0) {
            const int nv = (end - beg) >> 2;
            const int4* d4p = reinterpret_cast<const int4*>(dst + beg);
            const int4* s4p = reinterpret_cast<const int4*>(src + beg);
            for (int i = t; i < nv; i += 256) {
                const int4 d = d4p[i];
                const int4 s = s4p[i];
                int q;
                q = atomicAdd(&cur[d.x >> NPB_SHIFT], 1); ebuf[q] = make_int2(s.x, d.x);
                q = atomicAdd(&cur[d.y >> NPB_SHIFT], 1); ebuf[q] = make_int2(s.y, d.y);
                q = atomicAdd(&cur[d.z >> NPB_SHIFT], 1); ebuf[q] = make_int2(s.z, d.z);
                q = atomicAdd(&cur[d.w >> NPB_SHIFT], 1); ebuf[q] = make_int2(s.w, d.w);
            }
            for (int i = beg + (nv << 2) + t; i < end; i += 256) {
                const int d = dst[i];
                const int q = atomicAdd(&cur[d >> NPB_SHIFT], 1);
                ebuf[q] = make_int2(src[i], d);
            }
        } else {
            for (int i = beg + t; i < end; i += 256) {
                const int d = dst[i];
                const int q = atomicAdd(&cur[d >> NPB_SHIFT], 1);
                ebuf[q] = make_int2(src[i], d);
            }
        }
    }
}

__global__ __launch_bounds__(256) void k_p2(
        const int2* __restrict__ ebuf, const int* __restrict__ bb,
        int* __restrict__ rowptr, int* __restrict__ csr, int* __restrict__ gcur,
        int n, int nb) {
    __shared__ int lout[P2CAP];
    __shared__ int hc[NPB];
    __shared__ int sc[NPB];
    const int b = blockIdx.x;
    const int t = threadIdx.x;
    const int nodeBase = b << NPB_SHIFT;
    const int nEnd = (nodeBase + NPB < n) ? nodeBase + NPB : n;
    const int nloc = nEnd - nodeBase;
    const int rbeg = bb[b], rend = bb[b + 1];
    const int cnt = rend - rbeg;

    hc[t] = 0;
    __syncthreads();
    for (int p = rbeg + t; p < rend; p += 256)
        atomicAdd(&hc[ebuf[p].y - nodeBase], 1);
    __syncthreads();

    const int a = hc[t];
    sc[t] = a;
    __syncthreads();
    for (int off = 1; off < 256; off <<= 1) {
        int u = (t >= off) ? sc[t - off] : 0;
        __syncthreads();
        sc[t] += u;
        __syncthreads();
    }
    const int excl = sc[t] - a;
    if (t < nloc) rowptr[nodeBase + t] = rbeg + excl;
    if (b == nb - 1 && t == 0) rowptr[n] = rend;
    hc[t] = excl;
    __syncthreads();

    if (cnt <= P2CAP) {
        for (int p = rbeg + t; p < rend; p += 256) {
            const int2 sd = ebuf[p];
            const int q = atomicAdd(&hc[sd.y - nodeBase], 1);
            lout[q] = sd.x;
        }
        __syncthreads();
        for (int i = t; i < cnt; i += 256) csr[rbeg + i] = lout[i];
    } else {
        if (t < nloc) gcur[nodeBase + t] = rbeg + excl;
        __syncthreads();
        for (int p = rbeg + t; p < rend; p += 256) {
            const int2 sd = ebuf[p];
            const int q = atomicAdd(&gcur[sd.y], 1);
            csr[q] = sd.x;
        }
    }
}

// ---------------- V1 = BN(X*imp) @ W1  (BN-apply fused, 128->64, fp16 out) ----------------
__global__ __launch_bounds__(256) void k_pregemm(
        const float* __restrict__ X, const float* __restrict__ imp,
        const float* __restrict__ scale, const float* __restrict__ shift,
        const float* __restrict__ W1, __half* __restrict__ V1, int n) {
    __shared__ float tile[64 * 129];
    __shared__ float Wl[128 * 64];
    const int t = threadIdx.x;
    for (int i = t; i < 128 * 64 / 4; i += 256)
        reinterpret_cast<float4*>(Wl)[i] = reinterpret_cast<const float4*>(W1)[i];

    const int nodeL = t >> 2, q = t & 3;
    const int node = blockIdx.x * 64 + nodeL;
    if (node < n) {
        const float im = imp[node];
#pragma unroll
        for (int j = 0; j < 8; ++j) {
            const int c = q * 4 + j * 16;
            const float4 x  = *reinterpret_cast<const float4*>(X + (size_t)node * 128 + c);
            const float4 sc = *reinterpret_cast<const float4*>(scale + c);
            const float4 sh = *reinterpret_cast<const float4*>(shift + c);
            float* tr = tile + nodeL * 129 + c;
            tr[0] = fmaf(x.x * im, sc.x, sh.x);
            tr[1] = fmaf(x.y * im, sc.y, sh.y);
            tr[2] = fmaf(x.z * im, sc.z, sh.z);
            tr[3] = fmaf(x.w * im, sc.w, sh.w);
        }
    } else {
#pragma unroll
        for (int j = 0; j < 8; ++j) {
            const int c = q * 4 + j * 16;
            float* tr = tile + nodeL * 129 + c;
            tr[0] = 0.f; tr[1] = 0.f; tr[2] = 0.f; tr[3] = 0.f;
        }
    }
    __syncthreads();

    const int j0 = q * 16;
    float acc[16];
#pragma unroll
    for (int i = 0; i < 16; ++i) acc[i] = 0.f;
#pragma unroll 4
    for (int k = 0; k < 128; ++k) {
        const float ak = tile[nodeL * 129 + k];
        const float4* w = reinterpret_cast<const float4*>(Wl + k * 64 + j0);
#pragma unroll
        for (int i = 0; i < 4; ++i) {
            const float4 wv = w[i];
            acc[4 * i + 0] = fmaf(ak, wv.x, acc[4 * i + 0]);
            acc[4 * i + 1] = fmaf(ak, wv.y, acc[4 * i + 1]);
            acc[4 * i + 2] = fmaf(ak, wv.z, acc[4 * i + 2]);
            acc[4 * i + 3] = fmaf(ak, wv.w, acc[4 * i + 3]);
        }
    }
    if (node < n)
        store_h16(V1 + (size_t)node * 64 + j0, acc);
}

// ---------------- gather: h = tanh(V_self + sum_j V_j + b), fp16 rows ----------------
__global__ __launch_bounds__(256, 8) void k_gather(
        const __half* __restrict__ Vin, const float* __restrict__ bias,
        float* __restrict__ outh,    // d_out + col, row stride 384
        const int* __restrict__ rowptr, const int* __restrict__ csr, int n) {
    const int lane = threadIdx.x & 63;
    const int grp  = lane >> 4;
    const int gl4  = (lane & 15) << 2;
    const int w = blockIdx.x * 4 + (threadIdx.x >> 6);
    if (w >= n) return;

    float4 acc = make_float4(0.f, 0.f, 0.f, 0.f);
    if (grp == 0) {
        const uint2 u = *reinterpret_cast<const uint2*>(Vin + (size_t)w * 64 + gl4);
        acc = h4_to_f4(u);
    }

    const int beg = rowptr[w], end = rowptr[w + 1];
    int p = beg + grp;
    for (; p + 12 < end; p += 16) {
        const int s0 = csr[p];
        const int s1 = csr[p + 4];
        const int s2 = csr[p + 8];
        const int s3 = csr[p + 12];
        const uint2 u0 = *reinterpret_cast<const uint2*>(Vin + (size_t)s0 * 64 + gl4);
        const uint2 u1 = *reinterpret_cast<const uint2*>(Vin + (size_t)s1 * 64 + gl4);
        const uint2 u2 = *reinterpret_cast<const uint2*>(Vin + (size_t)s2 * 64 + gl4);
        const uint2 u3 = *reinterpret_cast<const uint2*>(Vin + (size_t)s3 * 64 + gl4);
        const float4 v0 = h4_to_f4(u0);
        const float4 v1 = h4_to_f4(u1);
        const float4 v2 = h4_to_f4(u2);
        const float4 v3 = h4_to_f4(u3);
        acc.x += v0.x + v1.x + v2.x + v3.x;
        acc.y += v0.y + v1.y + v2.y + v3.y;
        acc.z += v0.z + v1.z + v2.z + v3.z;
        acc.w += v0.w + v1.w + v2.w + v3.w;
    }
    for (; p < end; p += 4) {
        const int s = csr[p];
        const uint2 u = *reinterpret_cast<const uint2*>(Vin + (size_t)s * 64 + gl4);
        const float4 v = h4_to_f4(u);
        acc.x += v.x; acc.y += v.y; acc.z += v.z; acc.w += v.w;
    }

    acc.x += __shfl_xor(acc.x, 16); acc.y += __shfl_xor(acc.y, 16);
    acc.z += __shfl_xor(acc.z, 16); acc.w += __shfl_xor(acc.w, 16);
    acc.x += __shfl_xor(acc.x, 32); acc.y += __shfl_xor(acc.y, 32);
    acc.z += __shfl_xor(acc.z, 32); acc.w += __shfl_xor(acc.w, 32);

    if (grp == 0) {
        const float4 bb = *reinterpret_cast<const float4*>(bias + gl4);
        float4 r;
        r.x = tanh_fast(acc.x + bb.x);
        r.y = tanh_fast(acc.y + bb.y);
        r.z = tanh_fast(acc.z + bb.z);
        r.w = tanh_fast(acc.w + bb.w);
        *reinterpret_cast<float4*>(outh + (size_t)w * 384 + gl4) = r;
    }
}

// ---------------- dense: out = hin @ W ; 128-node tile, 2 nodes/thread ----------------
template <bool TANH, typename OutT>
__global__ __launch_bounds__(256) void k_dense(
        const float* __restrict__ hin, int in_stride,
        const float* __restrict__ W,
        OutT* __restrict__ outp, int out_stride, int n) {
    __shared__ float tile[128 * 65];
    __shared__ float Wl[64 * 64];
    const int t = threadIdx.x;
    for (int i = t; i < 64 * 64 / 4; i += 256)
        reinterpret_cast<float4*>(Wl)[i] = reinterpret_cast<const float4*>(W)[i];

    const int base = blockIdx.x * 128;
    {
        const int nodeL = t >> 1;
        const int c0 = (t & 1) * 32;
        const int node = base + nodeL;
        if (node < n) {
#pragma unroll
            for (int i = 0; i < 8; ++i) {
                const float4 v = *reinterpret_cast<const float4*>(
                    hin + (size_t)node * in_stride + c0 + 4 * i);
                float* tr = tile + nodeL * 65 + c0 + 4 * i;
                tr[0] = v.x; tr[1] = v.y; tr[2] = v.z; tr[3] = v.w;
            }
        } else {
#pragma unroll
            for (int i = 0; i < 32; ++i) tile[nodeL * 65 + c0 + i] = 0.f;
        }
    }
    __syncthreads();

    const int q = t & 3, j0 = q * 16;
    const int np = t >> 2;                 // 0..63 -> nodes 2np, 2np+1
    const float* r0 = tile + (2 * np) * 65;
    const float* r1 = r0 + 65;
    float acc0[16], acc1[16];
#pragma unroll
    for (int i = 0; i < 16; ++i) { acc0[i] = 0.f; acc1[i] = 0.f; }
#pragma unroll 4
    for (int k = 0; k < 64; ++k) {
        const float a0 = r0[k];
        const float a1 = r1[k];
        const float4* wr = reinterpret_cast<const float4*>(Wl + k * 64 + j0);
#pragma unroll
        for (int i = 0; i < 4; ++i) {
            const float4 wv = wr[i];
            acc0[4 * i + 0] = fmaf(a0, wv.x, acc0[4 * i + 0]);
            acc0[4 * i + 1] = fmaf(a0, wv.y, acc0[4 * i + 1]);
            acc0[4 * i + 2] = fmaf(a0, wv.z, acc0[4 * i + 2]);
            acc0[4 * i + 3] = fmaf(a0, wv.w, acc0[4 * i + 3]);
            acc1[4 * i + 0] = fmaf(a1, wv.x, acc1[4 * i + 0]);
            acc1[4 * i + 1] = fmaf(a1, wv.y, acc1[4 * i + 1]);
            acc1[4 * i + 2] = fmaf(a1, wv.z, acc1[4 * i + 2]);
            acc1[4 * i + 3] = fmaf(a1, wv.w, acc1[4 * i + 3]);
        }
    }
#pragma unroll
    for (int m = 0; m < 2; ++m) {
        const int node = base + 2 * np + m;
        if (node >= n) continue;
        float* a = m ? acc1 : acc0;
        OutT* o = outp + (size_t)node * out_stride + j0;
        if (TANH) {
#pragma unroll
            for (int i = 0; i < 16; ++i) a[i] = tanh_fast(a[i]);
        }
        if constexpr (sizeof(OutT) == 2) {
            store_h16((__half*)o, a);
        } else {
#pragma unroll
            for (int i = 0; i < 4; ++i)
                *reinterpret_cast<float4*>((float*)o + 4 * i) =
                    make_float4(a[4 * i], a[4 * i + 1], a[4 * i + 2], a[4 * i + 3]);
        }
    }
}

// ---------------- launch ----------------
extern "C" void kernel_launch(void* const* d_in, const int* in_sizes, int n_in,
                              void* d_out, int out_size, void* d_ws, size_t ws_size,
                              hipStream_t stream) {
    const float* X     = (const float*)d_in[0];
    const float* imp   = (const float*)d_in[1];
    const int*   ei    = (const int*)d_in[2];
    const float* gamma = (const float*)d_in[3];
    const float* beta  = (const float*)d_in[4];
    const float* W1 = (const float*)d_in[5];
    const float* b1 = (const float*)d_in[6];
    const float* W2 = (const float*)d_in[7];
    const float* b2 = (const float*)d_in[8];
    const float* W3 = (const float*)d_in[9];
    const float* b3 = (const float*)d_in[10];
    const float* W4 = (const float*)d_in[11];
    const float* b4 = (const float*)d_in[12];
    const float* W5 = (const float*)d_in[13];
    const float* b5 = (const float*)d_in[14];
    const float* Wf = (const float*)d_in[15];
    float* out = (float*)d_out;

    const int n = in_sizes[1];        // N
    const int e = in_sizes[2] / 2;    // E
    const int* src = ei;
    const int* dst = ei + e;
    const int nb = (n + NPB - 1) >> NPB_SHIFT;
    const int chunk = (((e + P1B - 1) / P1B) + 3) & ~3;

    // workspace carve (256B aligned)
    char* p = (char*)d_ws;
    auto carve = [&](size_t bytes) { char* r = p; p += (bytes + 255) & ~(size_t)255; return r; };
    int*   gh     = (int*)carve((size_t)P1B * MAXNB * sizeof(int));
    int*   bb     = (int*)carve((size_t)(MAXNB + 1) * sizeof(int));
    int*   rowptr = (int*)carve((size_t)(n + 1) * sizeof(int));
    int*   csr    = (int*)carve((size_t)e * sizeof(int));
    int*   gcur   = (int*)carve((size_t)n * sizeof(int));
    float* ps     = (float*)carve((size_t)STATS_B * 128 * sizeof(float));
    float* pq     = (float*)carve((size_t)STATS_B * 128 * sizeof(float));
    float* scale  = (float*)carve(128 * sizeof(float));
    float* shift  = (float*)carve(128 * sizeof(float));
    // VA/VB (fp16) overlaid with ebuf (disjoint lifetimes)
    char*  uni    = carve((size_t)e * sizeof(int2) > 2 * (size_t)n * 64 * sizeof(__half)
                          ? (size_t)e * sizeof(int2)
                          : 2 * (size_t)n * 64 * sizeof(__half));
    __half* VA    = (__half*)uni;
    __half* VB    = (__half*)(uni + (size_t)n * 64 * sizeof(__half));
    int2*  ebuf   = (int2*)uni;

    const int ntiles64  = (n + 63) / 64;
    const int ntiles128 = (n + 127) / 128;
    const int ngather = (n + 3) / 4;

    // BN stats
    k_stats<<<STATS_B, 256, 0, stream>>>(X, imp, ps, pq, n);
    k_finalize<<<1, 1024, 0, stream>>>(ps, pq, gamma, beta, scale, shift, STATS_B, 1.0f / (float)n);

    // atomic-free CSR build (counting sort by destination)
    k_p1cnt<<<P1B, 256, 0, stream>>>(dst, gh, e, nb, chunk);
    k_p1scan<<<1, MAXNB, 0, stream>>>(gh, bb, e, nb);
    k_p1scat<<<P1B, 256, 0, stream>>>(src, dst, gh, ebuf, e, nb, chunk);
    k_p2<<<nb, 256, 0, stream>>>(ebuf, bb, rowptr, csr, gcur, n, nb);

    // V1 = BN(X*imp) @ W1   (fp16 out; ebuf dead after k_p2)
    k_pregemm<<<ntiles64, 256, 0, stream>>>(X, imp, scale, shift, W1, VA, n);

    // layer l: h_l = tanh(V_self + sum V_j + b_l) -> out slice; V_{l+1} = h_l @ W_{l+1}
    k_gather<<<ngather, 256, 0, stream>>>(VA, b1, out + 0,   rowptr, csr, n);
    k_dense<false, __half><<<ntiles128, 256, 0, stream>>>(out + 0,   384, W2, VB, 64, n);
    k_gather<<<ngather, 256, 0, stream>>>(VB, b2, out + 64,  rowptr, csr, n);
    k_dense<false, __half><<<ntiles128, 256, 0, stream>>>(out + 64,  384, W3, VA, 64, n);
    k_gather<<<ngather, 256, 0, stream>>>(VA, b3, out + 128, rowptr, csr, n);
    k_dense<false, __half><<<ntiles128, 256, 0, stream>>>(out + 128, 384, W4, VB, 64, n);
    k_gather<<<ngather, 256, 0, stream>>>(VB, b4, out + 192, rowptr, csr, n);
    k_dense<false, __half><<<ntiles128, 256, 0, stream>>>(out + 192, 384, W5, VA, 64, n);
    k_gather<<<ngather, 256, 0, stream>>>(VA, b5, out + 256, rowptr, csr, n);
    k_dense<true, float><<<ntiles128, 256, 0, stream>>>(out + 256, 384, Wf, out + 320, 384, n);
}